// Round 1
// baseline (1353.510 us; speedup 1.0000x reference)
//
#include <hip/hip_runtime.h>
#include <cstdint>
#include <cstddef>

namespace {

constexpr int kB    = 64;
constexpr int kN    = 1024;
constexpr int kE    = 655360;
constexpr int kEper = kE / kB;     // 10240
constexpr int kH    = 128;
constexpr int kK1   = 820;
constexpr int kK2   = 656;
constexpr int kM1   = kB * kN;     // 65536
constexpr int kM2   = kB * kK1;    // 52480
constexpr int kM3   = kB * kK2;    // 41984

// ---- in-degree (optionally through inv mapping; em=1 per surviving edge) ----
__global__ void count_kernel(const int* __restrict__ src, const int* __restrict__ dst,
                             const int* __restrict__ inv, float* __restrict__ cnt, int nE) {
  int e = blockIdx.x * blockDim.x + threadIdx.x;
  if (e >= nE) return;
  int s = src[e], d = dst[e];
  if (inv) {
    s = inv[s]; d = inv[d];
    if (s < 0 || d < 0) return;
  }
  atomicAdd(&cnt[d], 1.0f);
}

__global__ void rcnt_kernel(float* cnt, int M) {
  int i = blockIdx.x * blockDim.x + threadIdx.x;
  if (i < M) cnt[i] = 1.0f / fmaxf(cnt[i], 1.0f);
}

// ---- per-(graph, 16-feature-chunk) LDS scatter-mean ----
// layer1: inv==null, feat=x, nloc=1024.  layer2: inv=inv1, feat=h1 (gated on the
// fly by gsc1[inv1[src]] since hp1[ns] == h1[src]*gsc1[ns]), nloc=820.
__global__ __launch_bounds__(256)
void scatter_kernel(const float* __restrict__ feat, const int* __restrict__ src,
                    const int* __restrict__ dst, const int* __restrict__ inv,
                    const float* __restrict__ gscale, const float* __restrict__ rcnt,
                    float* __restrict__ aggout, int nloc) {
  extern __shared__ float lbuf[];                 // nloc*16 floats
  const int chunk = blockIdx.x;
  const int g     = blockIdx.y;
  const int c0    = chunk * 16;
  const int tid   = threadIdx.x;
  const int tot   = nloc * 16;
  for (int i = tid; i < tot; i += 256) lbuf[i] = 0.0f;
  __syncthreads();
  const int f     = tid & 15;
  const int esub  = tid >> 4;
  const int ebase = g * kEper;
  const int gk    = g * nloc;
  for (int e0 = esub; e0 < kEper; e0 += 16) {
    const int e = ebase + e0;
    int s = src[e], d = dst[e];
    float sc = 1.0f;
    if (inv) {
      const int ns = inv[s], nd = inv[d];
      if (ns < 0 || nd < 0) continue;            // em == 0
      sc = gscale[ns];
      d  = nd;                                   // feat row stays original s
    }
    const float v = feat[(size_t)s * kH + c0 + f] * sc;
    atomicAdd(&lbuf[(d - gk) * 16 + f], v);
  }
  __syncthreads();
  for (int i = tid; i < tot; i += 256) {
    const int node = i >> 4, ff = i & 15;
    aggout[(size_t)(gk + node) * kH + c0 + ff] = lbuf[i] * rcnt[gk + node];
  }
}

// ---- out = relu(mean@Wl + x@Wr + b); 128x128 block tile, 8x8 per thread ----
// x rows optionally gathered+gated via (perm,gsc) for layer 2.
__global__ __launch_bounds__(256)
void sage_gemm(const float* __restrict__ meanb, const float* __restrict__ xsrc,
               const int* __restrict__ perm, const float* __restrict__ gsc,
               const float* __restrict__ Wl, const float* __restrict__ Wr,
               const float* __restrict__ bias, float* __restrict__ outp) {
  __shared__ float aT[32][132];   // [k][row], pad 132: conflict-free b128 reads over rows
  __shared__ float wT[32][128];   // [k][col]
  const int tid = threadIdx.x;
  const int jg  = tid & 15;
  const int rg  = tid >> 4;
  const int j0  = jg * 8;
  const int r0  = rg * 8;
  const int rowbase = blockIdx.x * 128;
  float acc[8][8];
#pragma unroll
  for (int a = 0; a < 8; ++a)
#pragma unroll
    for (int b = 0; b < 8; ++b) acc[a][b] = 0.0f;

  for (int kc = 0; kc < 8; ++kc) {               // 8 chunks of 32 k (0..127 mean, 128..255 x)
    const bool ismean = kc < 4;
    const float* sp = ismean ? meanb : xsrc;
    const float* wp = ismean ? Wl : Wr;
    const int kbase = ismean ? kc * 32 : kc * 32 - 128;
#pragma unroll
    for (int i = 0; i < 4; ++i) {                // stage A^T: 128 rows x 32 k
      const int p   = tid + i * 256;
      const int row = p >> 3;
      const int k4  = p & 7;
      const int grow = rowbase + row;
      int srow = grow; float scale = 1.0f;
      if (!ismean && perm) { srow = perm[grow]; scale = gsc[grow]; }
      const float4 v = *(const float4*)(sp + (size_t)srow * kH + kbase + k4 * 4);
      aT[k4 * 4 + 0][row] = v.x * scale;
      aT[k4 * 4 + 1][row] = v.y * scale;
      aT[k4 * 4 + 2][row] = v.z * scale;
      aT[k4 * 4 + 3][row] = v.w * scale;
    }
#pragma unroll
    for (int i = 0; i < 4; ++i) {                // stage W: 32 k x 128 cols
      const int p  = tid + i * 256;
      const int kk = p >> 5;
      const int j4 = p & 31;
      *(float4*)&wT[kk][j4 * 4] =
          *(const float4*)(wp + (size_t)(kbase + kk) * kH + j4 * 4);
    }
    __syncthreads();
#pragma unroll 4
    for (int k = 0; k < 32; ++k) {
      float a[8], w[8];
      *(float4*)&a[0] = *(const float4*)&aT[k][r0];
      *(float4*)&a[4] = *(const float4*)&aT[k][r0 + 4];
      *(float4*)&w[0] = *(const float4*)&wT[k][j0];
      *(float4*)&w[4] = *(const float4*)&wT[k][j0 + 4];
#pragma unroll
      for (int rr = 0; rr < 8; ++rr)
#pragma unroll
        for (int cc = 0; cc < 8; ++cc)
          acc[rr][cc] += a[rr] * w[cc];
    }
    __syncthreads();
  }
  float bv[8];
#pragma unroll
  for (int cc = 0; cc < 8; ++cc) bv[cc] = bias[j0 + cc];
#pragma unroll
  for (int rr = 0; rr < 8; ++rr) {
    const size_t row = (size_t)(rowbase + r0 + rr);
    float4 o0, o1;
    o0.x = fmaxf(acc[rr][0] + bv[0], 0.0f);
    o0.y = fmaxf(acc[rr][1] + bv[1], 0.0f);
    o0.z = fmaxf(acc[rr][2] + bv[2], 0.0f);
    o0.w = fmaxf(acc[rr][3] + bv[3], 0.0f);
    o1.x = fmaxf(acc[rr][4] + bv[4], 0.0f);
    o1.y = fmaxf(acc[rr][5] + bv[5], 0.0f);
    o1.z = fmaxf(acc[rr][6] + bv[6], 0.0f);
    o1.w = fmaxf(acc[rr][7] + bv[7], 0.0f);
    *(float4*)(outp + row * kH + j0)     = o0;
    *(float4*)(outp + row * kH + j0 + 4) = o1;
  }
}

// ---- score = tanh(h . w / ||w||), one wave per row ----
__global__ void score_kernel(const float* __restrict__ h, const float* __restrict__ w,
                             float* __restrict__ score, int M) {
  const int tid  = threadIdx.x;
  const int lane = tid & 63;
  const int r    = blockIdx.x * 4 + (tid >> 6);
  if (r >= M) return;
  const float2 v  = *(const float2*)(h + (size_t)r * kH + lane * 2);
  const float2 wv = *(const float2*)(w + lane * 2);
  float d = v.x * wv.x + v.y * wv.y;
  float n = wv.x * wv.x + wv.y * wv.y;
  for (int off = 32; off > 0; off >>= 1) {
    d += __shfl_down(d, off);
    n += __shfl_down(n, off);
  }
  if (lane == 0) score[r] = tanhf(d / sqrtf(n));
}

// ---- exact top-K per graph: O(n^2) rank + scan compaction ----
__global__ __launch_bounds__(1024)
void topk_kernel(const float* __restrict__ score, int n_per, int K,
                 int* __restrict__ inv, int* __restrict__ perm, float* __restrict__ gsc) {
  __shared__ float s[1024];
  __shared__ int   psum[1024];
  const int g = blockIdx.x, i = threadIdx.x;
  const float mys = (i < n_per) ? score[g * n_per + i] : -1e30f;
  s[i] = mys;
  __syncthreads();
  int rank = 0;
  for (int j = 0; j < n_per; ++j) {
    const float sj = s[j];
    rank += (sj > mys) || (sj == mys && j < i);   // lax.top_k tie semantics
  }
  const int keep = (i < n_per && rank < K) ? 1 : 0;
  psum[i] = keep;
  __syncthreads();
  for (int off = 1; off < 1024; off <<= 1) {
    int v = psum[i];
    if (i >= off) v += psum[i - off];
    __syncthreads();
    psum[i] = v;
    __syncthreads();
  }
  if (i < n_per) {
    const int pos = psum[i] - 1;                  // inclusive -> position
    inv[g * n_per + i] = keep ? (g * K + pos) : -1;
    if (keep) {
      perm[g * K + pos] = g * n_per + i;
      gsc[g * K + pos]  = mys;
    }
  }
}

// ---- fused gather+gate + mean/max readout: xout[g] = [mean, max] over K rows ----
__global__ __launch_bounds__(1024)
void readout_kernel(const float* __restrict__ h, const int* __restrict__ perm,
                    const float* __restrict__ gsc, int K, float* __restrict__ xout) {
  const int g = blockIdx.x, tid = threadIdx.x;
  const int j = tid & 127, part = tid >> 7;       // 8 row-parts
  float sum = 0.0f, mx = -1e30f;
  for (int r = part; r < K; r += 8) {
    const int   row = perm[g * K + r];
    const float sc  = gsc[g * K + r];
    const float v   = h[(size_t)row * kH + j] * sc;
    sum += v;
    mx = fmaxf(mx, v);
  }
  __shared__ float ssum[8][128], smax[8][128];
  ssum[part][j] = sum;
  smax[part][j] = mx;
  __syncthreads();
  if (part == 0) {
#pragma unroll
    for (int p = 1; p < 8; ++p) {
      sum += ssum[p][j];
      mx = fmaxf(mx, smax[p][j]);
    }
    xout[g * 256 + j]       = sum / (float)K;
    xout[g * 256 + 128 + j] = mx;
  }
}

// ---- z = relu((x1+x2)@fW1 + fb1); out = z@fW2 + fb2 ----
__global__ __launch_bounds__(128)
void final_mlp(const float* __restrict__ x1, const float* __restrict__ x2,
               const float* __restrict__ fW1, const float* __restrict__ fb1,
               const float* __restrict__ fW2, const float* __restrict__ fb2,
               float* __restrict__ out) {
  __shared__ float xx[256];
  __shared__ float z[128];
  const int g = blockIdx.x, tid = threadIdx.x;
  xx[tid]       = x1[g * 256 + tid]       + x2[g * 256 + tid];
  xx[tid + 128] = x1[g * 256 + 128 + tid] + x2[g * 256 + 128 + tid];
  __syncthreads();
  float a = fb1[tid];
  for (int k = 0; k < 256; ++k) a += xx[k] * fW1[k * 128 + tid];
  z[tid] = fmaxf(a, 0.0f);
  __syncthreads();
  if (tid < 10) {
    float o = fb2[tid];
    for (int k = 0; k < 128; ++k) o += z[k] * fW2[k * 10 + tid];
    out[g * 10 + tid] = o;
  }
}

}  // namespace

extern "C" void kernel_launch(void* const* d_in, const int* in_sizes, int n_in,
                              void* d_out, int out_size, void* d_ws, size_t ws_size,
                              hipStream_t stream) {
  const float* x   = (const float*)d_in[0];
  const int*   ei  = (const int*)d_in[1];
  const float* Wl1 = (const float*)d_in[3];
  const float* bl1 = (const float*)d_in[4];
  const float* Wr1 = (const float*)d_in[5];
  const float* Wl2 = (const float*)d_in[6];
  const float* bl2 = (const float*)d_in[7];
  const float* Wr2 = (const float*)d_in[8];
  const float* pw1 = (const float*)d_in[9];
  const float* pw2 = (const float*)d_in[10];
  const float* fW1 = (const float*)d_in[11];
  const float* fb1 = (const float*)d_in[12];
  const float* fW2 = (const float*)d_in[13];
  const float* fb2 = (const float*)d_in[14];
  const int* src = ei;
  const int* dst = ei + kE;
  (void)in_sizes; (void)n_in; (void)out_size; (void)ws_size;

  char* wsb = (char*)d_ws;
  size_t off = 0;
  auto alloc = [&](size_t bytes) {
    void* p = wsb + off;
    off += (bytes + 255) & ~(size_t)255;
    return p;
  };
  float* bufA = (float*)alloc((size_t)kM1 * kH * 4);  // mean1 -> mean2
  float* bufB = (float*)alloc((size_t)kM1 * kH * 4);  // h1
  float* bufC = (float*)alloc((size_t)kM2 * kH * 4);  // h2
  float* cnt  = (float*)alloc((size_t)kM1 * 4);       // deg -> 1/max(deg,1), reused
  float* scr  = (float*)alloc((size_t)kM1 * 4);
  int*   inv1 = (int*)alloc((size_t)kM1 * 4);
  int*   inv2 = (int*)alloc((size_t)kM2 * 4);
  int*   perm1= (int*)alloc((size_t)kM2 * 4);
  float* gsc1 = (float*)alloc((size_t)kM2 * 4);
  int*   perm2= (int*)alloc((size_t)kM3 * 4);
  float* gsc2 = (float*)alloc((size_t)kM3 * 4);
  float* x1   = (float*)alloc((size_t)kB * 256 * 4);
  float* x2   = (float*)alloc((size_t)kB * 256 * 4);

  // ---------------- layer 1 ----------------
  hipMemsetAsync(cnt, 0, (size_t)kM1 * 4, stream);
  count_kernel<<<kE / 256, 256, 0, stream>>>(src, dst, nullptr, cnt, kE);
  rcnt_kernel<<<kM1 / 256, 256, 0, stream>>>(cnt, kM1);
  scatter_kernel<<<dim3(8, kB), 256, kN * 16 * 4, stream>>>(
      x, src, dst, nullptr, nullptr, cnt, bufA, kN);
  sage_gemm<<<kM1 / 128, 256, 0, stream>>>(bufA, x, nullptr, nullptr,
                                           Wl1, Wr1, bl1, bufB);
  score_kernel<<<kM1 / 4, 256, 0, stream>>>(bufB, pw1, scr, kM1);
  topk_kernel<<<kB, 1024, 0, stream>>>(scr, kN, kK1, inv1, perm1, gsc1);
  readout_kernel<<<kB, 1024, 0, stream>>>(bufB, perm1, gsc1, kK1, x1);

  // ---------------- layer 2 ----------------
  hipMemsetAsync(cnt, 0, (size_t)kM2 * 4, stream);
  count_kernel<<<kE / 256, 256, 0, stream>>>(src, dst, inv1, cnt, kE);
  rcnt_kernel<<<(kM2 + 255) / 256, 256, 0, stream>>>(cnt, kM2);
  scatter_kernel<<<dim3(8, kB), 256, kK1 * 16 * 4, stream>>>(
      bufB, src, dst, inv1, gsc1, cnt, bufA, kK1);
  sage_gemm<<<kM2 / 128, 256, 0, stream>>>(bufA, bufB, perm1, gsc1,
                                           Wl2, Wr2, bl2, bufC);
  score_kernel<<<kM2 / 4, 256, 0, stream>>>(bufC, pw2, scr, kM2);
  topk_kernel<<<kB, 1024, 0, stream>>>(scr, kK1, kK2, inv2, perm2, gsc2);
  readout_kernel<<<kB, 1024, 0, stream>>>(bufC, perm2, gsc2, kK2, x2);

  // ---------------- head ----------------
  final_mlp<<<kB, 128, 0, stream>>>(x1, x2, fW1, fb1, fW2, fb2, (float*)d_out);
}

// Round 2
// 610.922 us; speedup vs baseline: 2.2155x; 2.2155x over previous
//
#include <hip/hip_runtime.h>
#include <cstdint>
#include <cstddef>

namespace {

constexpr int kB    = 64;
constexpr int kN    = 1024;
constexpr int kE    = 655360;
constexpr int kEper = kE / kB;     // 10240
constexpr int kH    = 128;
constexpr int kK1   = 820;
constexpr int kK2   = 656;
constexpr int kM1   = kB * kN;     // 65536
constexpr int kM2   = kB * kK1;    // 52480
constexpr int kM3   = kB * kK2;    // 41984

// ================= CSR build =================

// per-dst in-degree; layer2 maps through inv (edges with a removed endpoint drop)
__global__ void deg_kernel(const int* __restrict__ src, const int* __restrict__ dst,
                           const int* __restrict__ inv, int* __restrict__ deg) {
  int e = blockIdx.x * blockDim.x + threadIdx.x;
  if (e >= kE) return;
  int d = dst[e];
  if (inv) {
    const int ns = inv[src[e]];
    d = inv[d];
    if (ns < 0 || d < 0) return;
  }
  atomicAdd(&deg[d], 1);
}

// one block per graph: exclusive-scan the graph's degrees into global CSR offsets.
// graph g's CSR region is [g*kEper, ...) — always big enough (<=kEper edges/graph).
__global__ __launch_bounds__(1024)
void scan_kernel(const int* __restrict__ deg, int nloc,
                 int* __restrict__ off, int* __restrict__ cursor) {
  __shared__ int ps[1024];
  const int g = blockIdx.x, i = threadIdx.x;
  const int d = (i < nloc) ? deg[g * nloc + i] : 0;
  ps[i] = d;
  __syncthreads();
  for (int o = 1; o < 1024; o <<= 1) {
    int v = ps[i];
    if (i >= o) v += ps[i - o];
    __syncthreads();
    ps[i] = v;
    __syncthreads();
  }
  if (i < nloc) {
    const int start = g * kEper + ps[i] - d;   // exclusive scan
    off[g * nloc + i]    = start;
    cursor[g * nloc + i] = start;
  }
}

// entries: {feature-row index, gate-scale bits}
__global__ void fill1_kernel(const int* __restrict__ src, const int* __restrict__ dst,
                             int* __restrict__ cursor, int2* __restrict__ ent) {
  int e = blockIdx.x * blockDim.x + threadIdx.x;
  if (e >= kE) return;
  const int pos = atomicAdd(&cursor[dst[e]], 1);
  ent[pos] = make_int2(src[e], __float_as_int(1.0f));
}

// layer2: hp1[ns] == h1[perm1[ns]] * gsc1[ns], so store {perm1[ns], gsc1[ns]}
__global__ void fill2_kernel(const int* __restrict__ src, const int* __restrict__ dst,
                             const int* __restrict__ inv, const int* __restrict__ perm,
                             const float* __restrict__ gsc,
                             int* __restrict__ cursor, int2* __restrict__ ent) {
  int e = blockIdx.x * blockDim.x + threadIdx.x;
  if (e >= kE) return;
  const int ns = inv[src[e]], nd = inv[dst[e]];
  if (ns < 0 || nd < 0) return;
  const int pos = atomicAdd(&cursor[nd], 1);
  ent[pos] = make_int2(perm[ns], __float_as_int(gsc[ns]));
}

// ================= CSR gather-mean =================
// one wave per dst node; lane j accumulates features 2j,2j+1 (512 B/row, coalesced).
__global__ __launch_bounds__(256)
void gather_kernel(const float* __restrict__ feat, const int2* __restrict__ ent,
                   const int* __restrict__ off, const int* __restrict__ cursor,
                   float* __restrict__ aggout, int M) {
  const int lane = threadIdx.x & 63;
  const int node = blockIdx.x * 4 + (threadIdx.x >> 6);
  if (node >= M) return;
  const int o0 = off[node], o1 = cursor[node];   // cursor-off == degree
  float2 acc = make_float2(0.0f, 0.0f);
  int2 en = (o0 < o1) ? ent[o0] : make_int2(0, 0);
  for (int p = o0; p < o1; ++p) {
    const int2 cur = en;
    if (p + 1 < o1) en = ent[p + 1];             // prefetch next entry
    const float2 v = *(const float2*)(feat + (size_t)cur.x * kH + lane * 2);
    const float sc = __int_as_float(cur.y);
    acc.x += v.x * sc;
    acc.y += v.y * sc;
  }
  const float r = 1.0f / fmaxf((float)(o1 - o0), 1.0f);
  *(float2*)(aggout + (size_t)node * kH + lane * 2) = make_float2(acc.x * r, acc.y * r);
}

// ---- out = relu(mean@Wl + x@Wr + b); 128x128 block tile, 8x8 per thread ----
__global__ __launch_bounds__(256)
void sage_gemm(const float* __restrict__ meanb, const float* __restrict__ xsrc,
               const int* __restrict__ perm, const float* __restrict__ gsc,
               const float* __restrict__ Wl, const float* __restrict__ Wr,
               const float* __restrict__ bias, float* __restrict__ outp) {
  __shared__ float aT[32][132];   // [k][row], pad 132: conflict-free b128 reads over rows
  __shared__ float wT[32][128];   // [k][col]
  const int tid = threadIdx.x;
  const int jg  = tid & 15;
  const int rg  = tid >> 4;
  const int j0  = jg * 8;
  const int r0  = rg * 8;
  const int rowbase = blockIdx.x * 128;
  float acc[8][8];
#pragma unroll
  for (int a = 0; a < 8; ++a)
#pragma unroll
    for (int b = 0; b < 8; ++b) acc[a][b] = 0.0f;

  for (int kc = 0; kc < 8; ++kc) {               // 8 chunks of 32 k (0..127 mean, 128..255 x)
    const bool ismean = kc < 4;
    const float* sp = ismean ? meanb : xsrc;
    const float* wp = ismean ? Wl : Wr;
    const int kbase = ismean ? kc * 32 : kc * 32 - 128;
#pragma unroll
    for (int i = 0; i < 4; ++i) {                // stage A^T: 128 rows x 32 k
      const int p   = tid + i * 256;
      const int row = p >> 3;
      const int k4  = p & 7;
      const int grow = rowbase + row;
      int srow = grow; float scale = 1.0f;
      if (!ismean && perm) { srow = perm[grow]; scale = gsc[grow]; }
      const float4 v = *(const float4*)(sp + (size_t)srow * kH + kbase + k4 * 4);
      aT[k4 * 4 + 0][row] = v.x * scale;
      aT[k4 * 4 + 1][row] = v.y * scale;
      aT[k4 * 4 + 2][row] = v.z * scale;
      aT[k4 * 4 + 3][row] = v.w * scale;
    }
#pragma unroll
    for (int i = 0; i < 4; ++i) {                // stage W: 32 k x 128 cols
      const int p  = tid + i * 256;
      const int kk = p >> 5;
      const int j4 = p & 31;
      *(float4*)&wT[kk][j4 * 4] =
          *(const float4*)(wp + (size_t)(kbase + kk) * kH + j4 * 4);
    }
    __syncthreads();
#pragma unroll 4
    for (int k = 0; k < 32; ++k) {
      float a[8], w[8];
      *(float4*)&a[0] = *(const float4*)&aT[k][r0];
      *(float4*)&a[4] = *(const float4*)&aT[k][r0 + 4];
      *(float4*)&w[0] = *(const float4*)&wT[k][j0];
      *(float4*)&w[4] = *(const float4*)&wT[k][j0 + 4];
#pragma unroll
      for (int rr = 0; rr < 8; ++rr)
#pragma unroll
        for (int cc = 0; cc < 8; ++cc)
          acc[rr][cc] += a[rr] * w[cc];
    }
    __syncthreads();
  }
  float bv[8];
#pragma unroll
  for (int cc = 0; cc < 8; ++cc) bv[cc] = bias[j0 + cc];
#pragma unroll
  for (int rr = 0; rr < 8; ++rr) {
    const size_t row = (size_t)(rowbase + r0 + rr);
    float4 o0, o1;
    o0.x = fmaxf(acc[rr][0] + bv[0], 0.0f);
    o0.y = fmaxf(acc[rr][1] + bv[1], 0.0f);
    o0.z = fmaxf(acc[rr][2] + bv[2], 0.0f);
    o0.w = fmaxf(acc[rr][3] + bv[3], 0.0f);
    o1.x = fmaxf(acc[rr][4] + bv[4], 0.0f);
    o1.y = fmaxf(acc[rr][5] + bv[5], 0.0f);
    o1.z = fmaxf(acc[rr][6] + bv[6], 0.0f);
    o1.w = fmaxf(acc[rr][7] + bv[7], 0.0f);
    *(float4*)(outp + row * kH + j0)     = o0;
    *(float4*)(outp + row * kH + j0 + 4) = o1;
  }
}

// ---- score = tanh(h . w / ||w||), one wave per row ----
__global__ void score_kernel(const float* __restrict__ h, const float* __restrict__ w,
                             float* __restrict__ score, int M) {
  const int tid  = threadIdx.x;
  const int lane = tid & 63;
  const int r    = blockIdx.x * 4 + (tid >> 6);
  if (r >= M) return;
  const float2 v  = *(const float2*)(h + (size_t)r * kH + lane * 2);
  const float2 wv = *(const float2*)(w + lane * 2);
  float d = v.x * wv.x + v.y * wv.y;
  float n = wv.x * wv.x + wv.y * wv.y;
  for (int off = 32; off > 0; off >>= 1) {
    d += __shfl_down(d, off);
    n += __shfl_down(n, off);
  }
  if (lane == 0) score[r] = tanhf(d / sqrtf(n));
}

// ---- exact top-K per graph: O(n^2) rank + scan compaction ----
__global__ __launch_bounds__(1024)
void topk_kernel(const float* __restrict__ score, int n_per, int K,
                 int* __restrict__ inv, int* __restrict__ perm, float* __restrict__ gsc) {
  __shared__ float s[1024];
  __shared__ int   psum[1024];
  const int g = blockIdx.x, i = threadIdx.x;
  const float mys = (i < n_per) ? score[g * n_per + i] : -1e30f;
  s[i] = mys;
  __syncthreads();
  int rank = 0;
  for (int j = 0; j < n_per; ++j) {
    const float sj = s[j];
    rank += (sj > mys) || (sj == mys && j < i);   // lax.top_k tie semantics
  }
  const int keep = (i < n_per && rank < K) ? 1 : 0;
  psum[i] = keep;
  __syncthreads();
  for (int off = 1; off < 1024; off <<= 1) {
    int v = psum[i];
    if (i >= off) v += psum[i - off];
    __syncthreads();
    psum[i] = v;
    __syncthreads();
  }
  if (i < n_per) {
    const int pos = psum[i] - 1;                  // inclusive -> position
    inv[g * n_per + i] = keep ? (g * K + pos) : -1;
    if (keep) {
      perm[g * K + pos] = g * n_per + i;
      gsc[g * K + pos]  = mys;
    }
  }
}

// ---- fused gather+gate + mean/max readout: xout[g] = [mean, max] over K rows ----
__global__ __launch_bounds__(1024)
void readout_kernel(const float* __restrict__ h, const int* __restrict__ perm,
                    const float* __restrict__ gsc, int K, float* __restrict__ xout) {
  const int g = blockIdx.x, tid = threadIdx.x;
  const int j = tid & 127, part = tid >> 7;       // 8 row-parts
  float sum = 0.0f, mx = -1e30f;
  for (int r = part; r < K; r += 8) {
    const int   row = perm[g * K + r];
    const float sc  = gsc[g * K + r];
    const float v   = h[(size_t)row * kH + j] * sc;
    sum += v;
    mx = fmaxf(mx, v);
  }
  __shared__ float ssum[8][128], smax[8][128];
  ssum[part][j] = sum;
  smax[part][j] = mx;
  __syncthreads();
  if (part == 0) {
#pragma unroll
    for (int p = 1; p < 8; ++p) {
      sum += ssum[p][j];
      mx = fmaxf(mx, smax[p][j]);
    }
    xout[g * 256 + j]       = sum / (float)K;
    xout[g * 256 + 128 + j] = mx;
  }
}

// ---- z = relu((x1+x2)@fW1 + fb1); out = z@fW2 + fb2 ----
__global__ __launch_bounds__(128)
void final_mlp(const float* __restrict__ x1, const float* __restrict__ x2,
               const float* __restrict__ fW1, const float* __restrict__ fb1,
               const float* __restrict__ fW2, const float* __restrict__ fb2,
               float* __restrict__ out) {
  __shared__ float xx[256];
  __shared__ float z[128];
  const int g = blockIdx.x, tid = threadIdx.x;
  xx[tid]       = x1[g * 256 + tid]       + x2[g * 256 + tid];
  xx[tid + 128] = x1[g * 256 + 128 + tid] + x2[g * 256 + 128 + tid];
  __syncthreads();
  float a = fb1[tid];
  for (int k = 0; k < 256; ++k) a += xx[k] * fW1[k * 128 + tid];
  z[tid] = fmaxf(a, 0.0f);
  __syncthreads();
  if (tid < 10) {
    float o = fb2[tid];
    for (int k = 0; k < 128; ++k) o += z[k] * fW2[k * 10 + tid];
    out[g * 10 + tid] = o;
  }
}

}  // namespace

extern "C" void kernel_launch(void* const* d_in, const int* in_sizes, int n_in,
                              void* d_out, int out_size, void* d_ws, size_t ws_size,
                              hipStream_t stream) {
  const float* x   = (const float*)d_in[0];
  const int*   ei  = (const int*)d_in[1];
  const float* Wl1 = (const float*)d_in[3];
  const float* bl1 = (const float*)d_in[4];
  const float* Wr1 = (const float*)d_in[5];
  const float* Wl2 = (const float*)d_in[6];
  const float* bl2 = (const float*)d_in[7];
  const float* Wr2 = (const float*)d_in[8];
  const float* pw1 = (const float*)d_in[9];
  const float* pw2 = (const float*)d_in[10];
  const float* fW1 = (const float*)d_in[11];
  const float* fb1 = (const float*)d_in[12];
  const float* fW2 = (const float*)d_in[13];
  const float* fb2 = (const float*)d_in[14];
  const int* src = ei;
  const int* dst = ei + kE;
  (void)in_sizes; (void)n_in; (void)out_size; (void)ws_size;

  char* wsb = (char*)d_ws;
  size_t off_b = 0;
  auto alloc = [&](size_t bytes) {
    void* p = wsb + off_b;
    off_b += (bytes + 255) & ~(size_t)255;
    return p;
  };
  float* bufA = (float*)alloc((size_t)kM1 * kH * 4);  // mean1 -> mean2
  float* bufB = (float*)alloc((size_t)kM1 * kH * 4);  // h1
  float* bufC = (float*)alloc((size_t)kM2 * kH * 4);  // h2
  int*   deg  = (int*)alloc((size_t)kM1 * 4);
  int*   coff = (int*)alloc((size_t)kM1 * 4);
  int*   ccur = (int*)alloc((size_t)kM1 * 4);
  int2*  ent  = (int2*)alloc((size_t)kE * 8);
  float* scr  = (float*)alloc((size_t)kM1 * 4);
  int*   inv1 = (int*)alloc((size_t)kM1 * 4);
  int*   inv2 = (int*)alloc((size_t)kM2 * 4);
  int*   perm1= (int*)alloc((size_t)kM2 * 4);
  float* gsc1 = (float*)alloc((size_t)kM2 * 4);
  int*   perm2= (int*)alloc((size_t)kM3 * 4);
  float* gsc2 = (float*)alloc((size_t)kM3 * 4);
  float* x1   = (float*)alloc((size_t)kB * 256 * 4);
  float* x2   = (float*)alloc((size_t)kB * 256 * 4);

  // ---------------- layer 1 ----------------
  hipMemsetAsync(deg, 0, (size_t)kM1 * 4, stream);
  deg_kernel<<<kE / 256, 256, 0, stream>>>(src, dst, nullptr, deg);
  scan_kernel<<<kB, 1024, 0, stream>>>(deg, kN, coff, ccur);
  fill1_kernel<<<kE / 256, 256, 0, stream>>>(src, dst, ccur, ent);
  gather_kernel<<<kM1 / 4, 256, 0, stream>>>(x, ent, coff, ccur, bufA, kM1);
  sage_gemm<<<kM1 / 128, 256, 0, stream>>>(bufA, x, nullptr, nullptr,
                                           Wl1, Wr1, bl1, bufB);
  score_kernel<<<kM1 / 4, 256, 0, stream>>>(bufB, pw1, scr, kM1);
  topk_kernel<<<kB, 1024, 0, stream>>>(scr, kN, kK1, inv1, perm1, gsc1);
  readout_kernel<<<kB, 1024, 0, stream>>>(bufB, perm1, gsc1, kK1, x1);

  // ---------------- layer 2 ----------------
  hipMemsetAsync(deg, 0, (size_t)kM2 * 4, stream);
  deg_kernel<<<kE / 256, 256, 0, stream>>>(src, dst, inv1, deg);
  scan_kernel<<<kB, 1024, 0, stream>>>(deg, kK1, coff, ccur);
  fill2_kernel<<<kE / 256, 256, 0, stream>>>(src, dst, inv1, perm1, gsc1, ccur, ent);
  gather_kernel<<<(kM2 + 3) / 4, 256, 0, stream>>>(bufB, ent, coff, ccur, bufA, kM2);
  sage_gemm<<<kM2 / 128, 256, 0, stream>>>(bufA, bufB, perm1, gsc1,
                                           Wl2, Wr2, bl2, bufC);
  score_kernel<<<kM2 / 4, 256, 0, stream>>>(bufC, pw2, scr, kM2);
  topk_kernel<<<kB, 1024, 0, stream>>>(scr, kK1, kK2, inv2, perm2, gsc2);
  readout_kernel<<<kB, 1024, 0, stream>>>(bufC, perm2, gsc2, kK2, x2);

  // ---------------- head ----------------
  final_mlp<<<kB, 128, 0, stream>>>(x1, x2, fW1, fb1, fW2, fb2, (float*)d_out);
}

// Round 3
// 534.479 us; speedup vs baseline: 2.5324x; 1.1430x over previous
//
#include <hip/hip_runtime.h>
#include <cstdint>
#include <cstddef>

namespace {

constexpr int kB    = 64;
constexpr int kN    = 1024;
constexpr int kE    = 655360;
constexpr int kEper = kE / kB;     // 10240
constexpr int kH    = 128;
constexpr int kK1   = 820;
constexpr int kK2   = 656;
constexpr int kM1   = kB * kN;     // 65536
constexpr int kM2   = kB * kK1;    // 52480
constexpr int kM3   = kB * kK2;    // 41984

typedef __attribute__((ext_vector_type(8))) short bf16x8;
typedef __attribute__((ext_vector_type(4))) float f32x4;

__device__ inline ushort f2bf(float f) {            // fp32 -> bf16 RNE bits
  uint u = __float_as_uint(f);
  return (ushort)((u + 0x7fffu + ((u >> 16) & 1u)) >> 16);
}
__device__ inline float bf2f(ushort s) { return __uint_as_float(((uint)s) << 16); }

// ================= CSR build =================

__global__ void deg_kernel(const int* __restrict__ src, const int* __restrict__ dst,
                           const int* __restrict__ inv, int* __restrict__ deg) {
  int e = blockIdx.x * blockDim.x + threadIdx.x;
  if (e >= kE) return;
  int d = dst[e];
  if (inv) {
    const int ns = inv[src[e]];
    d = inv[d];
    if (ns < 0 || d < 0) return;
  }
  atomicAdd(&deg[d], 1);
}

// one block per graph: exclusive-scan the graph's degrees into global CSR offsets.
__global__ __launch_bounds__(1024)
void scan_kernel(const int* __restrict__ deg, int nloc,
                 int* __restrict__ off, int* __restrict__ cursor) {
  __shared__ int ps[1024];
  const int g = blockIdx.x, i = threadIdx.x;
  const int d = (i < nloc) ? deg[g * nloc + i] : 0;
  ps[i] = d;
  __syncthreads();
  for (int o = 1; o < 1024; o <<= 1) {
    int v = ps[i];
    if (i >= o) v += ps[i - o];
    __syncthreads();
    ps[i] = v;
    __syncthreads();
  }
  if (i < nloc) {
    const int start = g * kEper + ps[i] - d;   // exclusive scan
    off[g * nloc + i]    = start;
    cursor[g * nloc + i] = start;
  }
}

__global__ void fill1_kernel(const int* __restrict__ src, const int* __restrict__ dst,
                             int* __restrict__ cursor, int2* __restrict__ ent) {
  int e = blockIdx.x * blockDim.x + threadIdx.x;
  if (e >= kE) return;
  const int pos = atomicAdd(&cursor[dst[e]], 1);
  ent[pos] = make_int2(src[e], __float_as_int(1.0f));
}

// layer2: hp1[ns] == h1[perm1[ns]] * gsc1[ns]
__global__ void fill2_kernel(const int* __restrict__ src, const int* __restrict__ dst,
                             const int* __restrict__ inv, const int* __restrict__ perm,
                             const float* __restrict__ gsc,
                             int* __restrict__ cursor, int2* __restrict__ ent) {
  int e = blockIdx.x * blockDim.x + threadIdx.x;
  if (e >= kE) return;
  const int ns = inv[src[e]], nd = inv[dst[e]];
  if (ns < 0 || nd < 0) return;
  const int pos = atomicAdd(&cursor[nd], 1);
  ent[pos] = make_int2(perm[ns], __float_as_int(gsc[ns]));
}

// ================= CSR gather-mean, unroll-2 (two rows in flight) =================
__global__ __launch_bounds__(256)
void gather_kernel(const float* __restrict__ feat, const int2* __restrict__ ent,
                   const int* __restrict__ off, const int* __restrict__ cursor,
                   float* __restrict__ aggout, int M) {
  const int lane = threadIdx.x & 63;
  const int node = blockIdx.x * 4 + (threadIdx.x >> 6);
  if (node >= M) return;
  const int o0 = off[node], o1 = cursor[node];
  const int deg = o1 - o0;
  float2 a0 = make_float2(0.f, 0.f), a1 = make_float2(0.f, 0.f);
  int2 e0 = make_int2(0, 0), e1 = make_int2(0, 0);
  if (o0 < o1)     e0 = ent[o0];
  if (o0 + 1 < o1) e1 = ent[o0 + 1];
  int p = o0;
  for (; p + 2 <= o1; p += 2) {
    const int2 c0 = e0, c1 = e1;
    if (p + 2 < o1) e0 = ent[p + 2];
    if (p + 3 < o1) e1 = ent[p + 3];
    const float2 v0 = *(const float2*)(feat + (size_t)c0.x * kH + lane * 2);
    const float2 v1 = *(const float2*)(feat + (size_t)c1.x * kH + lane * 2);
    const float s0 = __int_as_float(c0.y), s1 = __int_as_float(c1.y);
    a0.x += v0.x * s0; a0.y += v0.y * s0;
    a1.x += v1.x * s1; a1.y += v1.y * s1;
  }
  if (p < o1) {
    const float2 v0 = *(const float2*)(feat + (size_t)e0.x * kH + lane * 2);
    const float s0 = __int_as_float(e0.y);
    a0.x += v0.x * s0; a0.y += v0.y * s0;
  }
  const float r = 1.0f / fmaxf((float)deg, 1.0f);
  *(float2*)(aggout + (size_t)node * kH + lane * 2) =
      make_float2((a0.x + a1.x) * r, (a0.y + a1.y) * r);
}

// ================= W pre-split: WT[n][k] = W[k][n] as bf16 hi/lo =================
// W stacked = [Wl (128x128); Wr (128x128)], k in [0,256), n in [0,128)
__global__ void wtprep_kernel(const float* __restrict__ Wl, const float* __restrict__ Wr,
                              ushort* __restrict__ WTh, ushort* __restrict__ WTl) {
  const int idx = blockIdx.x * 256 + threadIdx.x;   // 32768
  const int n = idx >> 8, k = idx & 255;
  const float w = (k < 128) ? Wl[k * kH + n] : Wr[(k - 128) * kH + n];
  const ushort h = f2bf(w);
  WTh[n * 256 + k] = h;
  WTl[n * 256 + k] = f2bf(w - bf2f(h));
}

// ================= split-bf16 MFMA SAGE GEMM =================
// out = relu([mean | gated-x] @ [Wl;Wr] + b), split precision:
//   C ≈ Ah@Wh + Ah@Wl + Al@Wh   (residual ~2^-18 relative)
// Block: 128 rows x 128 cols, 4 waves in 2x2; wave = 64x64 = 4x4 MFMA 16x16x32 tiles.
__global__ __launch_bounds__(256)
void sage_gemm_mfma(const float* __restrict__ meanb, const float* __restrict__ xsrc,
                    const int* __restrict__ perm, const float* __restrict__ gsc,
                    const ushort* __restrict__ WTh, const ushort* __restrict__ WTl,
                    const float* __restrict__ bias, float* __restrict__ outp) {
  __shared__ __align__(16) ushort aH[128][32];   // [row][k], 64 B row stride
  __shared__ __align__(16) ushort aL[128][32];
  __shared__ __align__(16) ushort wHs[128][32];  // [n][k] (= W^T)
  __shared__ __align__(16) ushort wLs[128][32];
  const int tid  = threadIdx.x;
  const int wid  = tid >> 6;
  const int lane = tid & 63;
  const int quad = lane >> 4;
  const int l16  = lane & 15;
  const int rowbase = blockIdx.x * 128;
  const int wr = (wid >> 1) * 64;                // wave row offset in tile
  const int wc = (wid & 1) * 64;                 // wave col offset

  f32x4 acc[4][4];
#pragma unroll
  for (int a = 0; a < 4; ++a)
#pragma unroll
    for (int b = 0; b < 4; ++b) acc[a][b] = (f32x4){0.f, 0.f, 0.f, 0.f};

  for (int s = 0; s < 8; ++s) {                  // 8 k-steps of 32 over K=256
    const bool ismean = s < 4;
    const float* sp = ismean ? meanb : xsrc;
    const int kbase = s * 32;
    const int kloc  = ismean ? kbase : kbase - 128;
    // ---- stage A (fp32 -> bf16 hi/lo): 128 rows x 32 k ----
#pragma unroll
    for (int i = 0; i < 4; ++i) {
      const int p   = tid + i * 256;
      const int row = p >> 3;
      const int k4  = (p & 7) * 4;
      const int grow = rowbase + row;
      int srow = grow; float scale = 1.0f;
      if (!ismean && perm) { srow = perm[grow]; scale = gsc[grow]; }
      const float4 v = *(const float4*)(sp + (size_t)srow * kH + kloc + k4);
      float f[4] = {v.x * scale, v.y * scale, v.z * scale, v.w * scale};
      ushort4 hv, lv;
      hv.x = f2bf(f[0]); lv.x = f2bf(f[0] - bf2f(hv.x));
      hv.y = f2bf(f[1]); lv.y = f2bf(f[1] - bf2f(hv.y));
      hv.z = f2bf(f[2]); lv.z = f2bf(f[2] - bf2f(hv.z));
      hv.w = f2bf(f[3]); lv.w = f2bf(f[3] - bf2f(hv.w));
      *(ushort4*)&aH[row][k4] = hv;
      *(ushort4*)&aL[row][k4] = lv;
    }
    // ---- stage W^T hi/lo: 128 n x 32 k ----
#pragma unroll
    for (int i = 0; i < 4; ++i) {
      const int p  = tid + i * 256;
      const int n  = p >> 3;
      const int k4 = (p & 7) * 4;
      *(ushort4*)&wHs[n][k4] = *(const ushort4*)(WTh + n * 256 + kbase + k4);
      *(ushort4*)&wLs[n][k4] = *(const ushort4*)(WTl + n * 256 + kbase + k4);
    }
    __syncthreads();
    // ---- compute ----
    bf16x8 afh[4], afl[4];
#pragma unroll
    for (int rt = 0; rt < 4; ++rt) {
      afh[rt] = *(const bf16x8*)&aH[wr + rt * 16 + l16][quad * 8];
      afl[rt] = *(const bf16x8*)&aL[wr + rt * 16 + l16][quad * 8];
    }
#pragma unroll
    for (int ct = 0; ct < 4; ++ct) {
      const bf16x8 bh = *(const bf16x8*)&wHs[wc + ct * 16 + l16][quad * 8];
      const bf16x8 bl = *(const bf16x8*)&wLs[wc + ct * 16 + l16][quad * 8];
#pragma unroll
      for (int rt = 0; rt < 4; ++rt) {
        acc[rt][ct] = __builtin_amdgcn_mfma_f32_16x16x32_bf16(afh[rt], bh, acc[rt][ct], 0, 0, 0);
        acc[rt][ct] = __builtin_amdgcn_mfma_f32_16x16x32_bf16(afh[rt], bl, acc[rt][ct], 0, 0, 0);
        acc[rt][ct] = __builtin_amdgcn_mfma_f32_16x16x32_bf16(afl[rt], bh, acc[rt][ct], 0, 0, 0);
      }
    }
    __syncthreads();
  }
  // ---- epilogue: bias + relu; C/D map col=lane&15, row=quad*4+reg ----
#pragma unroll
  for (int ct = 0; ct < 4; ++ct) {
    const int col = wc + ct * 16 + l16;
    const float bv = bias[col];
#pragma unroll
    for (int rt = 0; rt < 4; ++rt) {
#pragma unroll
      for (int reg = 0; reg < 4; ++reg) {
        const int row = rowbase + wr + rt * 16 + quad * 4 + reg;
        outp[(size_t)row * kH + col] = fmaxf(acc[rt][ct][reg] + bv, 0.0f);
      }
    }
  }
}

// ---- score = tanh(h . w / ||w||), one wave per row ----
__global__ void score_kernel(const float* __restrict__ h, const float* __restrict__ w,
                             float* __restrict__ score, int M) {
  const int tid  = threadIdx.x;
  const int lane = tid & 63;
  const int r    = blockIdx.x * 4 + (tid >> 6);
  if (r >= M) return;
  const float2 v  = *(const float2*)(h + (size_t)r * kH + lane * 2);
  const float2 wv = *(const float2*)(w + lane * 2);
  float d = v.x * wv.x + v.y * wv.y;
  float n = wv.x * wv.x + wv.y * wv.y;
  for (int off = 32; off > 0; off >>= 1) {
    d += __shfl_down(d, off);
    n += __shfl_down(n, off);
  }
  if (lane == 0) score[r] = tanhf(d / sqrtf(n));
}

// ---- exact top-K per graph: O(n^2) rank + scan compaction ----
__global__ __launch_bounds__(1024)
void topk_kernel(const float* __restrict__ score, int n_per, int K,
                 int* __restrict__ inv, int* __restrict__ perm, float* __restrict__ gsc) {
  __shared__ float s[1024];
  __shared__ int   psum[1024];
  const int g = blockIdx.x, i = threadIdx.x;
  const float mys = (i < n_per) ? score[g * n_per + i] : -1e30f;
  s[i] = mys;
  __syncthreads();
  int rank = 0;
  for (int j = 0; j < n_per; ++j) {
    const float sj = s[j];
    rank += (sj > mys) || (sj == mys && j < i);   // lax.top_k tie semantics
  }
  const int keep = (i < n_per && rank < K) ? 1 : 0;
  psum[i] = keep;
  __syncthreads();
  for (int off = 1; off < 1024; off <<= 1) {
    int v = psum[i];
    if (i >= off) v += psum[i - off];
    __syncthreads();
    psum[i] = v;
    __syncthreads();
  }
  if (i < n_per) {
    const int pos = psum[i] - 1;
    inv[g * n_per + i] = keep ? (g * K + pos) : -1;
    if (keep) {
      perm[g * K + pos] = g * n_per + i;
      gsc[g * K + pos]  = mys;
    }
  }
}

// ---- fused gather+gate + mean/max readout ----
__global__ __launch_bounds__(1024)
void readout_kernel(const float* __restrict__ h, const int* __restrict__ perm,
                    const float* __restrict__ gsc, int K, float* __restrict__ xout) {
  const int g = blockIdx.x, tid = threadIdx.x;
  const int j = tid & 127, part = tid >> 7;
  float sum = 0.0f, mx = -1e30f;
  for (int r = part; r < K; r += 8) {
    const int   row = perm[g * K + r];
    const float sc  = gsc[g * K + r];
    const float v   = h[(size_t)row * kH + j] * sc;
    sum += v;
    mx = fmaxf(mx, v);
  }
  __shared__ float ssum[8][128], smax[8][128];
  ssum[part][j] = sum;
  smax[part][j] = mx;
  __syncthreads();
  if (part == 0) {
#pragma unroll
    for (int p = 1; p < 8; ++p) {
      sum += ssum[p][j];
      mx = fmaxf(mx, smax[p][j]);
    }
    xout[g * 256 + j]       = sum / (float)K;
    xout[g * 256 + 128 + j] = mx;
  }
}

// ---- z = relu((x1+x2)@fW1 + fb1); out = z@fW2 + fb2 ----
__global__ __launch_bounds__(128)
void final_mlp(const float* __restrict__ x1, const float* __restrict__ x2,
               const float* __restrict__ fW1, const float* __restrict__ fb1,
               const float* __restrict__ fW2, const float* __restrict__ fb2,
               float* __restrict__ out) {
  __shared__ float xx[256];
  __shared__ float z[128];
  const int g = blockIdx.x, tid = threadIdx.x;
  xx[tid]       = x1[g * 256 + tid]       + x2[g * 256 + tid];
  xx[tid + 128] = x1[g * 256 + 128 + tid] + x2[g * 256 + 128 + tid];
  __syncthreads();
  float a = fb1[tid];
  for (int k = 0; k < 256; ++k) a += xx[k] * fW1[k * 128 + tid];
  z[tid] = fmaxf(a, 0.0f);
  __syncthreads();
  if (tid < 10) {
    float o = fb2[tid];
    for (int k = 0; k < 128; ++k) o += z[k] * fW2[k * 10 + tid];
    out[g * 10 + tid] = o;
  }
}

}  // namespace

extern "C" void kernel_launch(void* const* d_in, const int* in_sizes, int n_in,
                              void* d_out, int out_size, void* d_ws, size_t ws_size,
                              hipStream_t stream) {
  const float* x   = (const float*)d_in[0];
  const int*   ei  = (const int*)d_in[1];
  const float* Wl1 = (const float*)d_in[3];
  const float* bl1 = (const float*)d_in[4];
  const float* Wr1 = (const float*)d_in[5];
  const float* Wl2 = (const float*)d_in[6];
  const float* bl2 = (const float*)d_in[7];
  const float* Wr2 = (const float*)d_in[8];
  const float* pw1 = (const float*)d_in[9];
  const float* pw2 = (const float*)d_in[10];
  const float* fW1 = (const float*)d_in[11];
  const float* fb1 = (const float*)d_in[12];
  const float* fW2 = (const float*)d_in[13];
  const float* fb2 = (const float*)d_in[14];
  const int* src = ei;
  const int* dst = ei + kE;
  (void)in_sizes; (void)n_in; (void)out_size; (void)ws_size;

  char* wsb = (char*)d_ws;
  size_t off_b = 0;
  auto alloc = [&](size_t bytes) {
    void* p = wsb + off_b;
    off_b += (bytes + 255) & ~(size_t)255;
    return p;
  };
  float* bufA = (float*)alloc((size_t)kM1 * kH * 4);  // mean1 -> mean2
  float* bufB = (float*)alloc((size_t)kM1 * kH * 4);  // h1
  float* bufC = (float*)alloc((size_t)kM2 * kH * 4);  // h2
  int*   deg  = (int*)alloc((size_t)kM1 * 4);
  int*   coff = (int*)alloc((size_t)kM1 * 4);
  int*   ccur = (int*)alloc((size_t)kM1 * 4);
  int2*  ent  = (int2*)alloc((size_t)kE * 8);
  float* scr  = (float*)alloc((size_t)kM1 * 4);
  int*   inv1 = (int*)alloc((size_t)kM1 * 4);
  int*   inv2 = (int*)alloc((size_t)kM2 * 4);
  int*   perm1= (int*)alloc((size_t)kM2 * 4);
  float* gsc1 = (float*)alloc((size_t)kM2 * 4);
  int*   perm2= (int*)alloc((size_t)kM3 * 4);
  float* gsc2 = (float*)alloc((size_t)kM3 * 4);
  float* x1   = (float*)alloc((size_t)kB * 256 * 4);
  float* x2   = (float*)alloc((size_t)kB * 256 * 4);
  ushort* wt1h = (ushort*)alloc((size_t)128 * 256 * 2);
  ushort* wt1l = (ushort*)alloc((size_t)128 * 256 * 2);
  ushort* wt2h = (ushort*)alloc((size_t)128 * 256 * 2);
  ushort* wt2l = (ushort*)alloc((size_t)128 * 256 * 2);

  // weight pre-split (tiny; reused by both GEMMs)
  wtprep_kernel<<<128, 256, 0, stream>>>(Wl1, Wr1, wt1h, wt1l);
  wtprep_kernel<<<128, 256, 0, stream>>>(Wl2, Wr2, wt2h, wt2l);

  // ---------------- layer 1 ----------------
  hipMemsetAsync(deg, 0, (size_t)kM1 * 4, stream);
  deg_kernel<<<kE / 256, 256, 0, stream>>>(src, dst, nullptr, deg);
  scan_kernel<<<kB, 1024, 0, stream>>>(deg, kN, coff, ccur);
  fill1_kernel<<<kE / 256, 256, 0, stream>>>(src, dst, ccur, ent);
  gather_kernel<<<kM1 / 4, 256, 0, stream>>>(x, ent, coff, ccur, bufA, kM1);
  sage_gemm_mfma<<<kM1 / 128, 256, 0, stream>>>(bufA, x, nullptr, nullptr,
                                                wt1h, wt1l, bl1, bufB);
  score_kernel<<<kM1 / 4, 256, 0, stream>>>(bufB, pw1, scr, kM1);
  topk_kernel<<<kB, 1024, 0, stream>>>(scr, kN, kK1, inv1, perm1, gsc1);
  readout_kernel<<<kB, 1024, 0, stream>>>(bufB, perm1, gsc1, kK1, x1);

  // ---------------- layer 2 ----------------
  hipMemsetAsync(deg, 0, (size_t)kM2 * 4, stream);
  deg_kernel<<<kE / 256, 256, 0, stream>>>(src, dst, inv1, deg);
  scan_kernel<<<kB, 1024, 0, stream>>>(deg, kK1, coff, ccur);
  fill2_kernel<<<kE / 256, 256, 0, stream>>>(src, dst, inv1, perm1, gsc1, ccur, ent);
  gather_kernel<<<(kM2 + 3) / 4, 256, 0, stream>>>(bufB, ent, coff, ccur, bufA, kM2);
  sage_gemm_mfma<<<kM2 / 128, 256, 0, stream>>>(bufA, bufB, perm1, gsc1,
                                                wt2h, wt2l, bl2, bufC);
  score_kernel<<<kM2 / 4, 256, 0, stream>>>(bufC, pw2, scr, kM2);
  topk_kernel<<<kB, 1024, 0, stream>>>(scr, kK1, kK2, inv2, perm2, gsc2);
  readout_kernel<<<kB, 1024, 0, stream>>>(bufC, perm2, gsc2, kK2, x2);

  // ---------------- head ----------------
  final_mlp<<<kB, 128, 0, stream>>>(x1, x2, fW1, fb1, fW2, fb2, (float*)d_out);
}

// Round 4
// 471.282 us; speedup vs baseline: 2.8720x; 1.1341x over previous
//
#include <hip/hip_runtime.h>
#include <cstdint>
#include <cstddef>

namespace {

constexpr int kB    = 64;
constexpr int kN    = 1024;
constexpr int kE    = 655360;
constexpr int kEper = kE / kB;     // 10240
constexpr int kH    = 128;
constexpr int kK1   = 820;
constexpr int kK2   = 656;
constexpr int kM1   = kB * kN;     // 65536
constexpr int kM2   = kB * kK1;    // 52480
constexpr int kM3   = kB * kK2;    // 41984
constexpr int kRChunks = 16;       // readout row-chunks per graph

typedef __attribute__((ext_vector_type(8))) short bf16x8;
typedef __attribute__((ext_vector_type(4))) float f32x4;

__device__ inline ushort f2bf(float f) {            // fp32 -> bf16 RNE bits
  uint u = __float_as_uint(f);
  return (ushort)((u + 0x7fffu + ((u >> 16) & 1u)) >> 16);
}
__device__ inline float bf2f(ushort s) { return __uint_as_float(((uint)s) << 16); }

// ================= CSR build =================

__global__ void deg_kernel(const int* __restrict__ src, const int* __restrict__ dst,
                           const int* __restrict__ inv, int* __restrict__ deg) {
  int e = blockIdx.x * blockDim.x + threadIdx.x;
  if (e >= kE) return;
  int d = dst[e];
  if (inv) {
    const int ns = inv[src[e]];
    d = inv[d];
    if (ns < 0 || d < 0) return;
  }
  atomicAdd(&deg[d], 1);
}

// one block per graph: exclusive-scan the graph's degrees into global CSR offsets.
__global__ __launch_bounds__(1024)
void scan_kernel(const int* __restrict__ deg, int nloc,
                 int* __restrict__ off, int* __restrict__ cursor) {
  __shared__ int ps[1024];
  const int g = blockIdx.x, i = threadIdx.x;
  const int d = (i < nloc) ? deg[g * nloc + i] : 0;
  ps[i] = d;
  __syncthreads();
  for (int o = 1; o < 1024; o <<= 1) {
    int v = ps[i];
    if (i >= o) v += ps[i - o];
    __syncthreads();
    ps[i] = v;
    __syncthreads();
  }
  if (i < nloc) {
    const int start = g * kEper + ps[i] - d;   // exclusive scan
    off[g * nloc + i]    = start;
    cursor[g * nloc + i] = start;
  }
}

__global__ void fill1_kernel(const int* __restrict__ src, const int* __restrict__ dst,
                             int* __restrict__ cursor, int2* __restrict__ ent) {
  int e = blockIdx.x * blockDim.x + threadIdx.x;
  if (e >= kE) return;
  const int pos = atomicAdd(&cursor[dst[e]], 1);
  ent[pos] = make_int2(src[e], __float_as_int(1.0f));
}

// layer2: hp1[ns] == h1[perm1[ns]] * gsc1[ns]
__global__ void fill2_kernel(const int* __restrict__ src, const int* __restrict__ dst,
                             const int* __restrict__ inv, const int* __restrict__ perm,
                             const float* __restrict__ gsc,
                             int* __restrict__ cursor, int2* __restrict__ ent) {
  int e = blockIdx.x * blockDim.x + threadIdx.x;
  if (e >= kE) return;
  const int ns = inv[src[e]], nd = inv[dst[e]];
  if (ns < 0 || nd < 0) return;
  const int pos = atomicAdd(&cursor[nd], 1);
  ent[pos] = make_int2(perm[ns], __float_as_int(gsc[ns]));
}

// ================= CSR gather-mean, unroll-2, XCD-swizzled =================
// Block swizzle: blockIdx&7 -> XCD (round-robin dispatch heuristic); 8 graphs
// per XCD so each XCD's feature working set (~4 MB) fits its private L2.
// npb = nloc/4 blocks per graph (integer for 1024 and 820).
__global__ __launch_bounds__(256)
void gather_kernel(const float* __restrict__ feat, const int2* __restrict__ ent,
                   const int* __restrict__ off, const int* __restrict__ cursor,
                   float* __restrict__ aggout, int nloc, int npb) {
  const int lane  = threadIdx.x & 63;
  const int xcd   = blockIdx.x & 7;
  const int local = blockIdx.x >> 3;
  const int gsub  = local / npb;                 // 0..7
  const int graph = xcd * 8 + gsub;
  const int lnode = (local - gsub * npb) * 4 + (threadIdx.x >> 6);
  const int node  = graph * nloc + lnode;
  const int o0 = off[node], o1 = cursor[node];
  const int deg = o1 - o0;
  float2 a0 = make_float2(0.f, 0.f), a1 = make_float2(0.f, 0.f);
  int2 e0 = make_int2(0, 0), e1 = make_int2(0, 0);
  if (o0 < o1)     e0 = ent[o0];
  if (o0 + 1 < o1) e1 = ent[o0 + 1];
  int p = o0;
  for (; p + 2 <= o1; p += 2) {
    const int2 c0 = e0, c1 = e1;
    if (p + 2 < o1) e0 = ent[p + 2];
    if (p + 3 < o1) e1 = ent[p + 3];
    const float2 v0 = *(const float2*)(feat + (size_t)c0.x * kH + lane * 2);
    const float2 v1 = *(const float2*)(feat + (size_t)c1.x * kH + lane * 2);
    const float s0 = __int_as_float(c0.y), s1 = __int_as_float(c1.y);
    a0.x += v0.x * s0; a0.y += v0.y * s0;
    a1.x += v1.x * s1; a1.y += v1.y * s1;
  }
  if (p < o1) {
    const float2 v0 = *(const float2*)(feat + (size_t)e0.x * kH + lane * 2);
    const float s0 = __int_as_float(e0.y);
    a0.x += v0.x * s0; a0.y += v0.y * s0;
  }
  const float r = 1.0f / fmaxf((float)deg, 1.0f);
  *(float2*)(aggout + (size_t)node * kH + lane * 2) =
      make_float2((a0.x + a1.x) * r, (a0.y + a1.y) * r);
}

// ================= W pre-split: WT[n][k] = W[k][n] as bf16 hi/lo =================
__global__ void wtprep_kernel(const float* __restrict__ Wl, const float* __restrict__ Wr,
                              ushort* __restrict__ WTh, ushort* __restrict__ WTl) {
  const int idx = blockIdx.x * 256 + threadIdx.x;   // 32768
  const int n = idx >> 8, k = idx & 255;
  const float w = (k < 128) ? Wl[k * kH + n] : Wr[(k - 128) * kH + n];
  const ushort h = f2bf(w);
  WTh[n * 256 + k] = h;
  WTl[n * 256 + k] = f2bf(w - bf2f(h));
}

// ================= split-bf16 MFMA SAGE GEMM =================
__global__ __launch_bounds__(256)
void sage_gemm_mfma(const float* __restrict__ meanb, const float* __restrict__ xsrc,
                    const int* __restrict__ perm, const float* __restrict__ gsc,
                    const ushort* __restrict__ WTh, const ushort* __restrict__ WTl,
                    const float* __restrict__ bias, float* __restrict__ outp) {
  __shared__ __align__(16) ushort aH[128][32];   // [row][k], 64 B row stride
  __shared__ __align__(16) ushort aL[128][32];
  __shared__ __align__(16) ushort wHs[128][32];  // [n][k] (= W^T)
  __shared__ __align__(16) ushort wLs[128][32];
  const int tid  = threadIdx.x;
  const int wid  = tid >> 6;
  const int lane = tid & 63;
  const int quad = lane >> 4;
  const int l16  = lane & 15;
  const int rowbase = blockIdx.x * 128;
  const int wr = (wid >> 1) * 64;
  const int wc = (wid & 1) * 64;

  f32x4 acc[4][4];
#pragma unroll
  for (int a = 0; a < 4; ++a)
#pragma unroll
    for (int b = 0; b < 4; ++b) acc[a][b] = (f32x4){0.f, 0.f, 0.f, 0.f};

  for (int s = 0; s < 8; ++s) {                  // 8 k-steps of 32 over K=256
    const bool ismean = s < 4;
    const float* sp = ismean ? meanb : xsrc;
    const int kbase = s * 32;
    const int kloc  = ismean ? kbase : kbase - 128;
#pragma unroll
    for (int i = 0; i < 4; ++i) {
      const int p   = tid + i * 256;
      const int row = p >> 3;
      const int k4  = (p & 7) * 4;
      const int grow = rowbase + row;
      int srow = grow; float scale = 1.0f;
      if (!ismean && perm) { srow = perm[grow]; scale = gsc[grow]; }
      const float4 v = *(const float4*)(sp + (size_t)srow * kH + kloc + k4);
      float f[4] = {v.x * scale, v.y * scale, v.z * scale, v.w * scale};
      ushort4 hv, lv;
      hv.x = f2bf(f[0]); lv.x = f2bf(f[0] - bf2f(hv.x));
      hv.y = f2bf(f[1]); lv.y = f2bf(f[1] - bf2f(hv.y));
      hv.z = f2bf(f[2]); lv.z = f2bf(f[2] - bf2f(hv.z));
      hv.w = f2bf(f[3]); lv.w = f2bf(f[3] - bf2f(hv.w));
      *(ushort4*)&aH[row][k4] = hv;
      *(ushort4*)&aL[row][k4] = lv;
    }
#pragma unroll
    for (int i = 0; i < 4; ++i) {
      const int p  = tid + i * 256;
      const int n  = p >> 3;
      const int k4 = (p & 7) * 4;
      *(ushort4*)&wHs[n][k4] = *(const ushort4*)(WTh + n * 256 + kbase + k4);
      *(ushort4*)&wLs[n][k4] = *(const ushort4*)(WTl + n * 256 + kbase + k4);
    }
    __syncthreads();
    bf16x8 afh[4], afl[4];
#pragma unroll
    for (int rt = 0; rt < 4; ++rt) {
      afh[rt] = *(const bf16x8*)&aH[wr + rt * 16 + l16][quad * 8];
      afl[rt] = *(const bf16x8*)&aL[wr + rt * 16 + l16][quad * 8];
    }
#pragma unroll
    for (int ct = 0; ct < 4; ++ct) {
      const bf16x8 bh = *(const bf16x8*)&wHs[wc + ct * 16 + l16][quad * 8];
      const bf16x8 bl = *(const bf16x8*)&wLs[wc + ct * 16 + l16][quad * 8];
#pragma unroll
      for (int rt = 0; rt < 4; ++rt) {
        acc[rt][ct] = __builtin_amdgcn_mfma_f32_16x16x32_bf16(afh[rt], bh, acc[rt][ct], 0, 0, 0);
        acc[rt][ct] = __builtin_amdgcn_mfma_f32_16x16x32_bf16(afh[rt], bl, acc[rt][ct], 0, 0, 0);
        acc[rt][ct] = __builtin_amdgcn_mfma_f32_16x16x32_bf16(afl[rt], bh, acc[rt][ct], 0, 0, 0);
      }
    }
    __syncthreads();
  }
#pragma unroll
  for (int ct = 0; ct < 4; ++ct) {
    const int col = wc + ct * 16 + l16;
    const float bv = bias[col];
#pragma unroll
    for (int rt = 0; rt < 4; ++rt) {
#pragma unroll
      for (int reg = 0; reg < 4; ++reg) {
        const int row = rowbase + wr + rt * 16 + quad * 4 + reg;
        outp[(size_t)row * kH + col] = fmaxf(acc[rt][ct][reg] + bv, 0.0f);
      }
    }
  }
}

// ---- score = tanh(h . w / ||w||), one wave per row ----
__global__ void score_kernel(const float* __restrict__ h, const float* __restrict__ w,
                             float* __restrict__ score, int M) {
  const int tid  = threadIdx.x;
  const int lane = tid & 63;
  const int r    = blockIdx.x * 4 + (tid >> 6);
  if (r >= M) return;
  const float2 v  = *(const float2*)(h + (size_t)r * kH + lane * 2);
  const float2 wv = *(const float2*)(w + lane * 2);
  float d = v.x * wv.x + v.y * wv.y;
  float n = wv.x * wv.x + wv.y * wv.y;
  for (int off = 32; off > 0; off >>= 1) {
    d += __shfl_down(d, off);
    n += __shfl_down(n, off);
  }
  if (lane == 0) score[r] = tanhf(d / sqrtf(n));
}

// ---- exact top-K per graph: O(n^2) rank + scan compaction ----
__global__ __launch_bounds__(1024)
void topk_kernel(const float* __restrict__ score, int n_per, int K,
                 int* __restrict__ inv, int* __restrict__ perm, float* __restrict__ gsc) {
  __shared__ float s[1024];
  __shared__ int   psum[1024];
  const int g = blockIdx.x, i = threadIdx.x;
  const float mys = (i < n_per) ? score[g * n_per + i] : -1e30f;
  s[i] = mys;
  __syncthreads();
  int rank = 0;
  for (int j = 0; j < n_per; ++j) {
    const float sj = s[j];
    rank += (sj > mys) || (sj == mys && j < i);   // lax.top_k tie semantics
  }
  const int keep = (i < n_per && rank < K) ? 1 : 0;
  psum[i] = keep;
  __syncthreads();
  for (int off = 1; off < 1024; off <<= 1) {
    int v = psum[i];
    if (i >= off) v += psum[i - off];
    __syncthreads();
    psum[i] = v;
    __syncthreads();
  }
  if (i < n_per) {
    const int pos = psum[i] - 1;
    inv[g * n_per + i] = keep ? (g * K + pos) : -1;
    if (keep) {
      perm[g * K + pos] = g * n_per + i;
      gsc[g * K + pos]  = mys;
    }
  }
}

// ---- readout stage 1: per-(graph, row-chunk) partial mean/max over gated rows ----
__global__ __launch_bounds__(256)
void readout_part(const float* __restrict__ h, const int* __restrict__ perm,
                  const float* __restrict__ gsc, int K,
                  float* __restrict__ psum, float* __restrict__ pmax) {
  const int g     = blockIdx.x >> 4;
  const int chunk = blockIdx.x & (kRChunks - 1);
  const int j     = threadIdx.x & 127;
  const int part  = threadIdx.x >> 7;            // 2 parts
  const int rows  = (K + kRChunks - 1) / kRChunks;
  const int r0 = chunk * rows;
  const int r1 = min(r0 + rows, K);
  float sum = 0.0f, mx = -1e30f;
  for (int r = r0 + part; r < r1; r += 2) {
    const int   row = perm[g * K + r];
    const float sc  = gsc[g * K + r];
    const float v   = h[(size_t)row * kH + j] * sc;
    sum += v;
    mx = fmaxf(mx, v);
  }
  __shared__ float ss[2][128], sm[2][128];
  ss[part][j] = sum;
  sm[part][j] = mx;
  __syncthreads();
  if (part == 0) {
    sum += ss[1][j];
    mx = fmaxf(mx, sm[1][j]);
    psum[(size_t)blockIdx.x * 128 + j] = sum;
    pmax[(size_t)blockIdx.x * 128 + j] = mx;
  }
}

// ---- readout stage 2: combine chunks -> xout[g] = [mean | max] ----
__global__ __launch_bounds__(128)
void readout_fin(const float* __restrict__ psum, const float* __restrict__ pmax,
                 int K, float* __restrict__ xout) {
  const int g = blockIdx.x, j = threadIdx.x;
  float s = 0.0f, m = -1e30f;
#pragma unroll
  for (int c = 0; c < kRChunks; ++c) {
    s += psum[(size_t)(g * kRChunks + c) * 128 + j];
    m = fmaxf(m, pmax[(size_t)(g * kRChunks + c) * 128 + j]);
  }
  xout[g * 256 + j]       = s / (float)K;
  xout[g * 256 + 128 + j] = m;
}

// ---- z = relu((x1+x2)@fW1 + fb1); out = z@fW2 + fb2 ----
__global__ __launch_bounds__(128)
void final_mlp(const float* __restrict__ x1, const float* __restrict__ x2,
               const float* __restrict__ fW1, const float* __restrict__ fb1,
               const float* __restrict__ fW2, const float* __restrict__ fb2,
               float* __restrict__ out) {
  __shared__ float xx[256];
  __shared__ float z[128];
  const int g = blockIdx.x, tid = threadIdx.x;
  xx[tid]       = x1[g * 256 + tid]       + x2[g * 256 + tid];
  xx[tid + 128] = x1[g * 256 + 128 + tid] + x2[g * 256 + 128 + tid];
  __syncthreads();
  float a = fb1[tid];
  for (int k = 0; k < 256; ++k) a += xx[k] * fW1[k * 128 + tid];
  z[tid] = fmaxf(a, 0.0f);
  __syncthreads();
  if (tid < 10) {
    float o = fb2[tid];
    for (int k = 0; k < 128; ++k) o += z[k] * fW2[k * 10 + tid];
    out[g * 10 + tid] = o;
  }
}

}  // namespace

extern "C" void kernel_launch(void* const* d_in, const int* in_sizes, int n_in,
                              void* d_out, int out_size, void* d_ws, size_t ws_size,
                              hipStream_t stream) {
  const float* x   = (const float*)d_in[0];
  const int*   ei  = (const int*)d_in[1];
  const float* Wl1 = (const float*)d_in[3];
  const float* bl1 = (const float*)d_in[4];
  const float* Wr1 = (const float*)d_in[5];
  const float* Wl2 = (const float*)d_in[6];
  const float* bl2 = (const float*)d_in[7];
  const float* Wr2 = (const float*)d_in[8];
  const float* pw1 = (const float*)d_in[9];
  const float* pw2 = (const float*)d_in[10];
  const float* fW1 = (const float*)d_in[11];
  const float* fb1 = (const float*)d_in[12];
  const float* fW2 = (const float*)d_in[13];
  const float* fb2 = (const float*)d_in[14];
  const int* src = ei;
  const int* dst = ei + kE;
  (void)in_sizes; (void)n_in; (void)out_size; (void)ws_size;

  char* wsb = (char*)d_ws;
  size_t off_b = 0;
  auto alloc = [&](size_t bytes) {
    void* p = wsb + off_b;
    off_b += (bytes + 255) & ~(size_t)255;
    return p;
  };
  float* bufA = (float*)alloc((size_t)kM1 * kH * 4);  // mean1 -> mean2
  float* bufB = (float*)alloc((size_t)kM1 * kH * 4);  // h1
  float* bufC = (float*)alloc((size_t)kM2 * kH * 4);  // h2
  int*   deg  = (int*)alloc((size_t)kM1 * 4);
  int*   coff = (int*)alloc((size_t)kM1 * 4);
  int*   ccur = (int*)alloc((size_t)kM1 * 4);
  int2*  ent  = (int2*)alloc((size_t)kE * 8);
  float* scr  = (float*)alloc((size_t)kM1 * 4);
  int*   inv1 = (int*)alloc((size_t)kM1 * 4);
  int*   inv2 = (int*)alloc((size_t)kM2 * 4);
  int*   perm1= (int*)alloc((size_t)kM2 * 4);
  float* gsc1 = (float*)alloc((size_t)kM2 * 4);
  int*   perm2= (int*)alloc((size_t)kM3 * 4);
  float* gsc2 = (float*)alloc((size_t)kM3 * 4);
  float* x1   = (float*)alloc((size_t)kB * 256 * 4);
  float* x2   = (float*)alloc((size_t)kB * 256 * 4);
  float* psum = (float*)alloc((size_t)kB * kRChunks * 128 * 4);
  float* pmax = (float*)alloc((size_t)kB * kRChunks * 128 * 4);
  ushort* wt1h = (ushort*)alloc((size_t)128 * 256 * 2);
  ushort* wt1l = (ushort*)alloc((size_t)128 * 256 * 2);
  ushort* wt2h = (ushort*)alloc((size_t)128 * 256 * 2);
  ushort* wt2l = (ushort*)alloc((size_t)128 * 256 * 2);

  // weight pre-split (tiny; reused by both GEMMs)
  wtprep_kernel<<<128, 256, 0, stream>>>(Wl1, Wr1, wt1h, wt1l);
  wtprep_kernel<<<128, 256, 0, stream>>>(Wl2, Wr2, wt2h, wt2l);

  // ---------------- layer 1 ----------------
  hipMemsetAsync(deg, 0, (size_t)kM1 * 4, stream);
  deg_kernel<<<kE / 256, 256, 0, stream>>>(src, dst, nullptr, deg);
  scan_kernel<<<kB, 1024, 0, stream>>>(deg, kN, coff, ccur);
  fill1_kernel<<<kE / 256, 256, 0, stream>>>(src, dst, ccur, ent);
  gather_kernel<<<kM1 / 4, 256, 0, stream>>>(x, ent, coff, ccur, bufA, kN, kN / 4);
  sage_gemm_mfma<<<kM1 / 128, 256, 0, stream>>>(bufA, x, nullptr, nullptr,
                                                wt1h, wt1l, bl1, bufB);
  score_kernel<<<kM1 / 4, 256, 0, stream>>>(bufB, pw1, scr, kM1);
  topk_kernel<<<kB, 1024, 0, stream>>>(scr, kN, kK1, inv1, perm1, gsc1);
  readout_part<<<kB * kRChunks, 256, 0, stream>>>(bufB, perm1, gsc1, kK1, psum, pmax);
  readout_fin<<<kB, 128, 0, stream>>>(psum, pmax, kK1, x1);

  // ---------------- layer 2 ----------------
  hipMemsetAsync(deg, 0, (size_t)kM2 * 4, stream);
  deg_kernel<<<kE / 256, 256, 0, stream>>>(src, dst, inv1, deg);
  scan_kernel<<<kB, 1024, 0, stream>>>(deg, kK1, coff, ccur);
  fill2_kernel<<<kE / 256, 256, 0, stream>>>(src, dst, inv1, perm1, gsc1, ccur, ent);
  gather_kernel<<<kM2 / 4, 256, 0, stream>>>(bufB, ent, coff, ccur, bufA, kK1, kK1 / 4);
  sage_gemm_mfma<<<kM2 / 128, 256, 0, stream>>>(bufA, bufB, perm1, gsc1,
                                                wt2h, wt2l, bl2, bufC);
  score_kernel<<<kM2 / 4, 256, 0, stream>>>(bufC, pw2, scr, kM2);
  topk_kernel<<<kB, 1024, 0, stream>>>(scr, kK1, kK2, inv2, perm2, gsc2);
  readout_part<<<kB * kRChunks, 256, 0, stream>>>(bufC, perm2, gsc2, kK2, psum, pmax);
  readout_fin<<<kB, 128, 0, stream>>>(psum, pmax, kK2, x2);

  // ---------------- head ----------------
  final_mlp<<<kB, 128, 0, stream>>>(x1, x2, fW1, fb1, fW2, fb2, (float*)d_out);
}

// Round 5
// 444.159 us; speedup vs baseline: 3.0474x; 1.0611x over previous
//
#include <hip/hip_runtime.h>
#include <cstdint>
#include <cstddef>

namespace {

constexpr int kB    = 64;
constexpr int kN    = 1024;
constexpr int kE    = 655360;
constexpr int kEper = kE / kB;     // 10240
constexpr int kH    = 128;
constexpr int kK1   = 820;
constexpr int kK2   = 656;
constexpr int kM1   = kB * kN;     // 65536
constexpr int kM2   = kB * kK1;    // 52480
constexpr int kM3   = kB * kK2;    // 41984
constexpr int kRChunks = 16;       // readout row-chunks per graph

typedef __attribute__((ext_vector_type(8))) short bf16x8;
typedef __attribute__((ext_vector_type(4))) float f32x4;

__device__ inline ushort f2bf(float f) {            // fp32 -> bf16 RNE bits
  uint u = __float_as_uint(f);
  return (ushort)((u + 0x7fffu + ((u >> 16) & 1u)) >> 16);
}
__device__ inline float bf2f(ushort s) { return __uint_as_float(((uint)s) << 16); }

// ================= CSR build =================

__global__ void deg_kernel(const int* __restrict__ src, const int* __restrict__ dst,
                           const int* __restrict__ inv, int* __restrict__ deg) {
  int e = blockIdx.x * blockDim.x + threadIdx.x;
  if (e >= kE) return;
  int d = dst[e];
  if (inv) {
    const int ns = inv[src[e]];
    d = inv[d];
    if (ns < 0 || d < 0) return;
  }
  atomicAdd(&deg[d], 1);
}

// one block per graph: exclusive-scan the graph's degrees into global CSR offsets.
__global__ __launch_bounds__(1024)
void scan_kernel(const int* __restrict__ deg, int nloc,
                 int* __restrict__ off, int* __restrict__ cursor) {
  __shared__ int ps[1024];
  const int g = blockIdx.x, i = threadIdx.x;
  const int d = (i < nloc) ? deg[g * nloc + i] : 0;
  ps[i] = d;
  __syncthreads();
  for (int o = 1; o < 1024; o <<= 1) {
    int v = ps[i];
    if (i >= o) v += ps[i - o];
    __syncthreads();
    ps[i] = v;
    __syncthreads();
  }
  if (i < nloc) {
    const int start = g * kEper + ps[i] - d;   // exclusive scan
    off[g * nloc + i]    = start;
    cursor[g * nloc + i] = start;
  }
}

__global__ void fill1_kernel(const int* __restrict__ src, const int* __restrict__ dst,
                             int* __restrict__ cursor, int2* __restrict__ ent) {
  int e = blockIdx.x * blockDim.x + threadIdx.x;
  if (e >= kE) return;
  const int pos = atomicAdd(&cursor[dst[e]], 1);
  ent[pos] = make_int2(src[e], __float_as_int(1.0f));
}

// layer2: hp1[ns] == h1[perm1[ns]] * gsc1[ns]
__global__ void fill2_kernel(const int* __restrict__ src, const int* __restrict__ dst,
                             const int* __restrict__ inv, const int* __restrict__ perm,
                             const float* __restrict__ gsc,
                             int* __restrict__ cursor, int2* __restrict__ ent) {
  int e = blockIdx.x * blockDim.x + threadIdx.x;
  if (e >= kE) return;
  const int ns = inv[src[e]], nd = inv[dst[e]];
  if (ns < 0 || nd < 0) return;
  const int pos = atomicAdd(&cursor[nd], 1);
  ent[pos] = make_int2(perm[ns], __float_as_int(gsc[ns]));
}

// guarded entry load: past-end -> {row 0, scale 0}. NEVER index past-end slots:
// unfilled ent gaps are 0xAA-poisoned (wild row index -> OOB feature read).
__device__ inline int2 entg(const int2* __restrict__ ent, int p, int o1) {
  if (p < o1) return ent[p];
  return make_int2(0, 0);
}

// ================= CSR gather-mean =================
// Half-wave per node (lanes 0-31 node A, 32-63 node B), float4 per lane:
// one dwordx4 load fetches TWO feature rows. Entries prefetched 2 iters ahead,
// rows 1 iter ahead -> row-load latency overlapped with a full iteration.
// XCD swizzle: blockIdx&7 -> XCD, 8 graphs/XCD (working set ~4 MB = L2).
// npb = ceil(nloc/8) blocks per graph; grid = 64*npb.
__global__ __launch_bounds__(256)
void gather_kernel(const float* __restrict__ feat, const int2* __restrict__ ent,
                   const int* __restrict__ off, const int* __restrict__ cursor,
                   float* __restrict__ aggout, int nloc, int npb) {
  const int xcd   = blockIdx.x & 7;
  const int local = blockIdx.x >> 3;
  const int gsub  = local / npb;                 // 0..7
  const int graph = xcd * 8 + gsub;
  const int lane  = threadIdx.x & 63;
  const int h     = lane >> 5;                   // node within pair
  const int l     = lane & 31;                   // feature quarter (floats l*4..l*4+3)
  const int wid   = threadIdx.x >> 6;
  const int lnode = (local - gsub * npb) * 8 + wid * 2 + h;
  if (lnode >= nloc) return;
  const int node = graph * nloc + lnode;
  const int o0 = off[node], o1 = cursor[node];
  const float r = 1.0f / fmaxf((float)(o1 - o0), 1.0f);
  float4 acc = make_float4(0.f, 0.f, 0.f, 0.f);

  int p = o0;
  int2 e0 = entg(ent, p, o1);                    // current entries
  int2 e1 = entg(ent, p + 1, o1);
  float4 v0 = *(const float4*)(feat + (size_t)e0.x * kH + l * 4);
  float4 v1 = *(const float4*)(feat + (size_t)e1.x * kH + l * 4);
  int2 n0 = entg(ent, p + 2, o1);                // next entries (1 iter ahead)
  int2 n1 = entg(ent, p + 3, o1);

  for (; p < o1; p += 2) {
    const int2 m0 = entg(ent, p + 4, o1);        // next-next entries
    const int2 m1 = entg(ent, p + 5, o1);
    const float4 w0 = *(const float4*)(feat + (size_t)n0.x * kH + l * 4);
    const float4 w1 = *(const float4*)(feat + (size_t)n1.x * kH + l * 4);
    const float s0 = __int_as_float(e0.y), s1 = __int_as_float(e1.y);
    acc.x += v0.x * s0; acc.y += v0.y * s0; acc.z += v0.z * s0; acc.w += v0.w * s0;
    acc.x += v1.x * s1; acc.y += v1.y * s1; acc.z += v1.z * s1; acc.w += v1.w * s1;
    e0 = n0; e1 = n1; n0 = m0; n1 = m1; v0 = w0; v1 = w1;
  }
  *(float4*)(aggout + (size_t)node * kH + l * 4) =
      make_float4(acc.x * r, acc.y * r, acc.z * r, acc.w * r);
}

// ================= W pre-split: WT[n][k] = W[k][n] as bf16 hi/lo =================
__global__ void wtprep_kernel(const float* __restrict__ Wl, const float* __restrict__ Wr,
                              ushort* __restrict__ WTh, ushort* __restrict__ WTl) {
  const int idx = blockIdx.x * 256 + threadIdx.x;   // 32768
  const int n = idx >> 8, k = idx & 255;
  const float w = (k < 128) ? Wl[k * kH + n] : Wr[(k - 128) * kH + n];
  const ushort h = f2bf(w);
  WTh[n * 256 + k] = h;
  WTl[n * 256 + k] = f2bf(w - bf2f(h));
}

// ================= split-bf16 MFMA SAGE GEMM =================
__global__ __launch_bounds__(256)
void sage_gemm_mfma(const float* __restrict__ meanb, const float* __restrict__ xsrc,
                    const int* __restrict__ perm, const float* __restrict__ gsc,
                    const ushort* __restrict__ WTh, const ushort* __restrict__ WTl,
                    const float* __restrict__ bias, float* __restrict__ outp) {
  __shared__ __align__(16) ushort aH[128][32];   // [row][k], 64 B row stride
  __shared__ __align__(16) ushort aL[128][32];
  __shared__ __align__(16) ushort wHs[128][32];  // [n][k] (= W^T)
  __shared__ __align__(16) ushort wLs[128][32];
  const int tid  = threadIdx.x;
  const int wid  = tid >> 6;
  const int lane = tid & 63;
  const int quad = lane >> 4;
  const int l16  = lane & 15;
  const int rowbase = blockIdx.x * 128;
  const int wr = (wid >> 1) * 64;
  const int wc = (wid & 1) * 64;

  f32x4 acc[4][4];
#pragma unroll
  for (int a = 0; a < 4; ++a)
#pragma unroll
    for (int b = 0; b < 4; ++b) acc[a][b] = (f32x4){0.f, 0.f, 0.f, 0.f};

  for (int s = 0; s < 8; ++s) {                  // 8 k-steps of 32 over K=256
    const bool ismean = s < 4;
    const float* sp = ismean ? meanb : xsrc;
    const int kbase = s * 32;
    const int kloc  = ismean ? kbase : kbase - 128;
#pragma unroll
    for (int i = 0; i < 4; ++i) {
      const int p   = tid + i * 256;
      const int row = p >> 3;
      const int k4  = (p & 7) * 4;
      const int grow = rowbase + row;
      int srow = grow; float scale = 1.0f;
      if (!ismean && perm) { srow = perm[grow]; scale = gsc[grow]; }
      const float4 v = *(const float4*)(sp + (size_t)srow * kH + kloc + k4);
      float f[4] = {v.x * scale, v.y * scale, v.z * scale, v.w * scale};
      ushort4 hv, lv;
      hv.x = f2bf(f[0]); lv.x = f2bf(f[0] - bf2f(hv.x));
      hv.y = f2bf(f[1]); lv.y = f2bf(f[1] - bf2f(hv.y));
      hv.z = f2bf(f[2]); lv.z = f2bf(f[2] - bf2f(hv.z));
      hv.w = f2bf(f[3]); lv.w = f2bf(f[3] - bf2f(hv.w));
      *(ushort4*)&aH[row][k4] = hv;
      *(ushort4*)&aL[row][k4] = lv;
    }
#pragma unroll
    for (int i = 0; i < 4; ++i) {
      const int p  = tid + i * 256;
      const int n  = p >> 3;
      const int k4 = (p & 7) * 4;
      *(ushort4*)&wHs[n][k4] = *(const ushort4*)(WTh + n * 256 + kbase + k4);
      *(ushort4*)&wLs[n][k4] = *(const ushort4*)(WTl + n * 256 + kbase + k4);
    }
    __syncthreads();
    bf16x8 afh[4], afl[4];
#pragma unroll
    for (int rt = 0; rt < 4; ++rt) {
      afh[rt] = *(const bf16x8*)&aH[wr + rt * 16 + l16][quad * 8];
      afl[rt] = *(const bf16x8*)&aL[wr + rt * 16 + l16][quad * 8];
    }
#pragma unroll
    for (int ct = 0; ct < 4; ++ct) {
      const bf16x8 bh = *(const bf16x8*)&wHs[wc + ct * 16 + l16][quad * 8];
      const bf16x8 bl = *(const bf16x8*)&wLs[wc + ct * 16 + l16][quad * 8];
#pragma unroll
      for (int rt = 0; rt < 4; ++rt) {
        acc[rt][ct] = __builtin_amdgcn_mfma_f32_16x16x32_bf16(afh[rt], bh, acc[rt][ct], 0, 0, 0);
        acc[rt][ct] = __builtin_amdgcn_mfma_f32_16x16x32_bf16(afh[rt], bl, acc[rt][ct], 0, 0, 0);
        acc[rt][ct] = __builtin_amdgcn_mfma_f32_16x16x32_bf16(afl[rt], bh, acc[rt][ct], 0, 0, 0);
      }
    }
    __syncthreads();
  }
#pragma unroll
  for (int ct = 0; ct < 4; ++ct) {
    const int col = wc + ct * 16 + l16;
    const float bv = bias[col];
#pragma unroll
    for (int rt = 0; rt < 4; ++rt) {
#pragma unroll
      for (int reg = 0; reg < 4; ++reg) {
        const int row = rowbase + wr + rt * 16 + quad * 4 + reg;
        outp[(size_t)row * kH + col] = fmaxf(acc[rt][ct][reg] + bv, 0.0f);
      }
    }
  }
}

// ---- score = tanh(h . w / ||w||), one wave per row ----
__global__ void score_kernel(const float* __restrict__ h, const float* __restrict__ w,
                             float* __restrict__ score, int M) {
  const int tid  = threadIdx.x;
  const int lane = tid & 63;
  const int r    = blockIdx.x * 4 + (tid >> 6);
  if (r >= M) return;
  const float2 v  = *(const float2*)(h + (size_t)r * kH + lane * 2);
  const float2 wv = *(const float2*)(w + lane * 2);
  float d = v.x * wv.x + v.y * wv.y;
  float n = wv.x * wv.x + wv.y * wv.y;
  for (int off = 32; off > 0; off >>= 1) {
    d += __shfl_down(d, off);
    n += __shfl_down(n, off);
  }
  if (lane == 0) score[r] = tanhf(d / sqrtf(n));
}

// ---- exact top-K per graph: O(n^2) rank (float4 LDS broadcast) + scan ----
__global__ __launch_bounds__(1024)
void topk_kernel(const float* __restrict__ score, int n_per, int K,
                 int* __restrict__ inv, int* __restrict__ perm, float* __restrict__ gsc) {
  __shared__ __align__(16) float s[1024];
  __shared__ int psum[1024];
  const int g = blockIdx.x, i = threadIdx.x;
  const float mys = (i < n_per) ? score[g * n_per + i] : -1e30f;
  s[i] = (i < n_per) ? mys : -3e30f;             // pad never outranks
  __syncthreads();
  int rank = 0;
  const int n4 = (n_per + 3) & ~3;
  for (int j = 0; j < n4; j += 4) {
    const float4 sj = *(const float4*)&s[j];
    rank += (sj.x > mys) || (sj.x == mys && (j + 0) < i);
    rank += (sj.y > mys) || (sj.y == mys && (j + 1) < i);
    rank += (sj.z > mys) || (sj.z == mys && (j + 2) < i);
    rank += (sj.w > mys) || (sj.w == mys && (j + 3) < i);
  }
  const int keep = (i < n_per && rank < K) ? 1 : 0;
  psum[i] = keep;
  __syncthreads();
  for (int off = 1; off < 1024; off <<= 1) {
    int v = psum[i];
    if (i >= off) v += psum[i - off];
    __syncthreads();
    psum[i] = v;
    __syncthreads();
  }
  if (i < n_per) {
    const int pos = psum[i] - 1;
    inv[g * n_per + i] = keep ? (g * K + pos) : -1;
    if (keep) {
      perm[g * K + pos] = g * n_per + i;
      gsc[g * K + pos]  = mys;
    }
  }
}

// ---- readout stage 1: per-(graph, row-chunk) partial mean/max over gated rows ----
__global__ __launch_bounds__(256)
void readout_part(const float* __restrict__ h, const int* __restrict__ perm,
                  const float* __restrict__ gsc, int K,
                  float* __restrict__ psum, float* __restrict__ pmax) {
  const int g     = blockIdx.x >> 4;
  const int chunk = blockIdx.x & (kRChunks - 1);
  const int j     = threadIdx.x & 127;
  const int part  = threadIdx.x >> 7;            // 2 parts
  const int rows  = (K + kRChunks - 1) / kRChunks;
  const int r0 = chunk * rows;
  const int r1 = min(r0 + rows, K);
  float sum = 0.0f, mx = -1e30f;
  for (int r = r0 + part; r < r1; r += 2) {
    const int   row = perm[g * K + r];
    const float sc  = gsc[g * K + r];
    const float v   = h[(size_t)row * kH + j] * sc;
    sum += v;
    mx = fmaxf(mx, v);
  }
  __shared__ float ss[2][128], sm[2][128];
  ss[part][j] = sum;
  sm[part][j] = mx;
  __syncthreads();
  if (part == 0) {
    sum += ss[1][j];
    mx = fmaxf(mx, sm[1][j]);
    psum[(size_t)blockIdx.x * 128 + j] = sum;
    pmax[(size_t)blockIdx.x * 128 + j] = mx;
  }
}

// ---- readout stage 2: combine chunks -> xout[g] = [mean | max] ----
__global__ __launch_bounds__(128)
void readout_fin(const float* __restrict__ psum, const float* __restrict__ pmax,
                 int K, float* __restrict__ xout) {
  const int g = blockIdx.x, j = threadIdx.x;
  float s = 0.0f, m = -1e30f;
#pragma unroll
  for (int c = 0; c < kRChunks; ++c) {
    s += psum[(size_t)(g * kRChunks + c) * 128 + j];
    m = fmaxf(m, pmax[(size_t)(g * kRChunks + c) * 128 + j]);
  }
  xout[g * 256 + j]       = s / (float)K;
  xout[g * 256 + 128 + j] = m;
}

// ---- z = relu((x1+x2)@fW1 + fb1); out = z@fW2 + fb2 ----
__global__ __launch_bounds__(128)
void final_mlp(const float* __restrict__ x1, const float* __restrict__ x2,
               const float* __restrict__ fW1, const float* __restrict__ fb1,
               const float* __restrict__ fW2, const float* __restrict__ fb2,
               float* __restrict__ out) {
  __shared__ float xx[256];
  __shared__ float z[128];
  const int g = blockIdx.x, tid = threadIdx.x;
  xx[tid]       = x1[g * 256 + tid]       + x2[g * 256 + tid];
  xx[tid + 128] = x1[g * 256 + 128 + tid] + x2[g * 256 + 128 + tid];
  __syncthreads();
  float a = fb1[tid];
  for (int k = 0; k < 256; ++k) a += xx[k] * fW1[k * 128 + tid];
  z[tid] = fmaxf(a, 0.0f);
  __syncthreads();
  if (tid < 10) {
    float o = fb2[tid];
    for (int k = 0; k < 128; ++k) o += z[k] * fW2[k * 10 + tid];
    out[g * 10 + tid] = o;
  }
}

}  // namespace

extern "C" void kernel_launch(void* const* d_in, const int* in_sizes, int n_in,
                              void* d_out, int out_size, void* d_ws, size_t ws_size,
                              hipStream_t stream) {
  const float* x   = (const float*)d_in[0];
  const int*   ei  = (const int*)d_in[1];
  const float* Wl1 = (const float*)d_in[3];
  const float* bl1 = (const float*)d_in[4];
  const float* Wr1 = (const float*)d_in[5];
  const float* Wl2 = (const float*)d_in[6];
  const float* bl2 = (const float*)d_in[7];
  const float* Wr2 = (const float*)d_in[8];
  const float* pw1 = (const float*)d_in[9];
  const float* pw2 = (const float*)d_in[10];
  const float* fW1 = (const float*)d_in[11];
  const float* fb1 = (const float*)d_in[12];
  const float* fW2 = (const float*)d_in[13];
  const float* fb2 = (const float*)d_in[14];
  const int* src = ei;
  const int* dst = ei + kE;
  (void)in_sizes; (void)n_in; (void)out_size; (void)ws_size;

  char* wsb = (char*)d_ws;
  size_t off_b = 0;
  auto alloc = [&](size_t bytes) {
    void* p = wsb + off_b;
    off_b += (bytes + 255) & ~(size_t)255;
    return p;
  };
  float* bufA = (float*)alloc((size_t)kM1 * kH * 4);  // mean1 -> mean2
  float* bufB = (float*)alloc((size_t)kM1 * kH * 4);  // h1
  float* bufC = (float*)alloc((size_t)kM2 * kH * 4);  // h2
  int*   deg  = (int*)alloc((size_t)kM1 * 4);
  int*   coff = (int*)alloc((size_t)kM1 * 4);
  int*   ccur = (int*)alloc((size_t)kM1 * 4);
  int2*  ent  = (int2*)alloc((size_t)kE * 8);
  float* scr  = (float*)alloc((size_t)kM1 * 4);
  int*   inv1 = (int*)alloc((size_t)kM1 * 4);
  int*   inv2 = (int*)alloc((size_t)kM2 * 4);
  int*   perm1= (int*)alloc((size_t)kM2 * 4);
  float* gsc1 = (float*)alloc((size_t)kM2 * 4);
  int*   perm2= (int*)alloc((size_t)kM3 * 4);
  float* gsc2 = (float*)alloc((size_t)kM3 * 4);
  float* x1   = (float*)alloc((size_t)kB * 256 * 4);
  float* x2   = (float*)alloc((size_t)kB * 256 * 4);
  float* psum = (float*)alloc((size_t)kB * kRChunks * 128 * 4);
  float* pmax = (float*)alloc((size_t)kB * kRChunks * 128 * 4);
  ushort* wt1h = (ushort*)alloc((size_t)128 * 256 * 2);
  ushort* wt1l = (ushort*)alloc((size_t)128 * 256 * 2);
  ushort* wt2h = (ushort*)alloc((size_t)128 * 256 * 2);
  ushort* wt2l = (ushort*)alloc((size_t)128 * 256 * 2);

  // weight pre-split (tiny; reused by both GEMMs)
  wtprep_kernel<<<128, 256, 0, stream>>>(Wl1, Wr1, wt1h, wt1l);
  wtprep_kernel<<<128, 256, 0, stream>>>(Wl2, Wr2, wt2h, wt2l);

  const int npb1 = kN / 8;             // 128
  const int npb2 = (kK1 + 7) / 8;      // 103

  // ---------------- layer 1 ----------------
  hipMemsetAsync(deg, 0, (size_t)kM1 * 4, stream);
  deg_kernel<<<kE / 256, 256, 0, stream>>>(src, dst, nullptr, deg);
  scan_kernel<<<kB, 1024, 0, stream>>>(deg, kN, coff, ccur);
  fill1_kernel<<<kE / 256, 256, 0, stream>>>(src, dst, ccur, ent);
  gather_kernel<<<64 * npb1, 256, 0, stream>>>(x, ent, coff, ccur, bufA, kN, npb1);
  sage_gemm_mfma<<<kM1 / 128, 256, 0, stream>>>(bufA, x, nullptr, nullptr,
                                                wt1h, wt1l, bl1, bufB);
  score_kernel<<<kM1 / 4, 256, 0, stream>>>(bufB, pw1, scr, kM1);
  topk_kernel<<<kB, 1024, 0, stream>>>(scr, kN, kK1, inv1, perm1, gsc1);
  readout_part<<<kB * kRChunks, 256, 0, stream>>>(bufB, perm1, gsc1, kK1, psum, pmax);
  readout_fin<<<kB, 128, 0, stream>>>(psum, pmax, kK1, x1);

  // ---------------- layer 2 ----------------
  hipMemsetAsync(deg, 0, (size_t)kM2 * 4, stream);
  deg_kernel<<<kE / 256, 256, 0, stream>>>(src, dst, inv1, deg);
  scan_kernel<<<kB, 1024, 0, stream>>>(deg, kK1, coff, ccur);
  fill2_kernel<<<kE / 256, 256, 0, stream>>>(src, dst, inv1, perm1, gsc1, ccur, ent);
  gather_kernel<<<64 * npb2, 256, 0, stream>>>(bufB, ent, coff, ccur, bufA, kK1, npb2);
  sage_gemm_mfma<<<kM2 / 128, 256, 0, stream>>>(bufA, bufB, perm1, gsc1,
                                                wt2h, wt2l, bl2, bufC);
  score_kernel<<<kM2 / 4, 256, 0, stream>>>(bufC, pw2, scr, kM2);
  topk_kernel<<<kB, 1024, 0, stream>>>(scr, kK1, kK2, inv2, perm2, gsc2);
  readout_part<<<kB * kRChunks, 256, 0, stream>>>(bufC, perm2, gsc2, kK2, psum, pmax);
  readout_fin<<<kB, 128, 0, stream>>>(psum, pmax, kK2, x2);

  // ---------------- head ----------------
  final_mlp<<<kB, 128, 0, stream>>>(x1, x2, fW1, fb1, fW2, fb2, (float*)d_out);
}

// Round 7
// 387.142 us; speedup vs baseline: 3.4962x; 1.1473x over previous
//
#include <hip/hip_runtime.h>
#include <cstdint>
#include <cstddef>

namespace {

constexpr int kB    = 64;
constexpr int kN    = 1024;
constexpr int kE    = 655360;
constexpr int kEper = kE / kB;     // 10240
constexpr int kH    = 128;
constexpr int kK1   = 820;
constexpr int kK2   = 656;
constexpr int kM1   = kB * kN;     // 65536
constexpr int kM2   = kB * kK1;    // 52480
constexpr int kM3   = kB * kK2;    // 41984
constexpr int kRChunks = 16;       // readout row-chunks per graph

typedef __attribute__((ext_vector_type(8))) short bf16x8;
typedef __attribute__((ext_vector_type(4))) float f32x4;

__device__ inline ushort f2bf(float f) {            // fp32 -> bf16 RNE bits
  uint u = __float_as_uint(f);
  return (ushort)((u + 0x7fffu + ((u >> 16) & 1u)) >> 16);
}
__device__ inline float bf2f(ushort s) { return __uint_as_float(((uint)s) << 16); }

// ================= prep: W^T hi/lo split + pw normalize =================
// blocks 0-127: layer1 W; 128-255: layer2 W; block 256: pw1/pw2 normalize.
__global__ __launch_bounds__(256)
void prep_kernel(const float* __restrict__ Wl1, const float* __restrict__ Wr1,
                 const float* __restrict__ Wl2, const float* __restrict__ Wr2,
                 const float* __restrict__ pw1, const float* __restrict__ pw2,
                 ushort* __restrict__ W1h, ushort* __restrict__ W1l,
                 ushort* __restrict__ W2h, ushort* __restrict__ W2l,
                 float* __restrict__ pwn1, float* __restrict__ pwn2) {
  const int tid = threadIdx.x;
  if (blockIdx.x == 256) {
    __shared__ float sq[256];
    const float* pw = (tid < 128) ? pw1 : pw2;
    const int j = tid & 127;
    const float v = pw[j];
    sq[tid] = v * v;
    __syncthreads();
    const int base = (tid < 128) ? 0 : 128;
    float sum = 0.0f;
    for (int k = 0; k < 128; ++k) sum += sq[base + k];
    float* o = (tid < 128) ? pwn1 : pwn2;
    o[j] = v / sqrtf(sum);
    return;
  }
  const bool l2 = blockIdx.x >= 128;
  const int idx = (blockIdx.x & 127) * 256 + tid;   // 0..32767
  const int n = idx >> 8, k = idx & 255;
  const float* Wl = l2 ? Wl2 : Wl1;
  const float* Wr = l2 ? Wr2 : Wr1;
  const float w = (k < 128) ? Wl[k * kH + n] : Wr[(k - 128) * kH + n];
  const ushort h = f2bf(w);
  (l2 ? W2h : W1h)[n * 256 + k] = h;
  (l2 ? W2l : W1l)[n * 256 + k] = f2bf(w - bf2f(h));
}

// ================= layer-1 CSR build =================
__global__ void deg_kernel(const int* __restrict__ dst, int* __restrict__ deg) {
  int e = blockIdx.x * blockDim.x + threadIdx.x;
  if (e >= kE) return;
  atomicAdd(&deg[dst[e]], 1);
}

__global__ __launch_bounds__(1024)
void scan_kernel(const int* __restrict__ deg, int nloc,
                 int* __restrict__ off, int* __restrict__ cursor) {
  __shared__ int ps[1024];
  const int g = blockIdx.x, i = threadIdx.x;
  const int d = (i < nloc) ? deg[g * nloc + i] : 0;
  ps[i] = d;
  __syncthreads();
  for (int o = 1; o < 1024; o <<= 1) {
    int v = ps[i];
    if (i >= o) v += ps[i - o];
    __syncthreads();
    ps[i] = v;
    __syncthreads();
  }
  if (i < nloc) {
    const int start = g * kEper + ps[i] - d;   // exclusive scan
    off[g * nloc + i]    = start;
    cursor[g * nloc + i] = start;
  }
}

__global__ void fill1_kernel(const int* __restrict__ src, const int* __restrict__ dst,
                             int* __restrict__ cursor, int* __restrict__ ent) {
  int e = blockIdx.x * blockDim.x + threadIdx.x;
  if (e >= kE) return;
  const int pos = atomicAdd(&cursor[dst[e]], 1);
  ent[pos] = src[e];
}

// guarded entry: past-end -> row 0 (valid memory; contribution masked by caller).
__device__ inline int eg(const int* __restrict__ ent, int p, int o1) {
  return (p < o1) ? ent[p] : 0;
}

// ================= layer-1 gather-mean (4 entries/iter, 8 loads in flight) ====
// Half-wave per node (lanes 0-31 node A, 32-63 node B), float4/lane.
// XCD swizzle: blockIdx&7 -> XCD, 8 graphs/XCD.
__global__ __launch_bounds__(256)
void gather1_kernel(const float* __restrict__ feat, const int* __restrict__ ent,
                    const int* __restrict__ off, const int* __restrict__ cursor,
                    float* __restrict__ aggout, int nloc, int npb) {
  const int xcd   = blockIdx.x & 7;
  const int local = blockIdx.x >> 3;
  const int gsub  = local / npb;
  const int graph = xcd * 8 + gsub;
  const int lane  = threadIdx.x & 63;
  const int h     = lane >> 5;
  const int l     = lane & 31;
  const int wid   = threadIdx.x >> 6;
  const int lnode = (local - gsub * npb) * 8 + wid * 2 + h;
  if (lnode >= nloc) return;
  const int node = graph * nloc + lnode;
  const int o0 = off[node], o1 = cursor[node];
  const float r = 1.0f / fmaxf((float)(o1 - o0), 1.0f);
  float4 acc = make_float4(0.f, 0.f, 0.f, 0.f);

  int e[4], n[4];
  float4 v[4];
#pragma unroll
  for (int i = 0; i < 4; ++i) e[i] = eg(ent, o0 + i, o1);
#pragma unroll
  for (int i = 0; i < 4; ++i) v[i] = *(const float4*)(feat + (size_t)e[i] * kH + l * 4);
#pragma unroll
  for (int i = 0; i < 4; ++i) n[i] = eg(ent, o0 + 4 + i, o1);

  for (int p = o0; p < o1; p += 4) {
    int m[4];
    float4 w[4];
#pragma unroll
    for (int i = 0; i < 4; ++i) m[i] = eg(ent, p + 8 + i, o1);
#pragma unroll
    for (int i = 0; i < 4; ++i) w[i] = *(const float4*)(feat + (size_t)n[i] * kH + l * 4);
#pragma unroll
    for (int i = 0; i < 4; ++i) {
      const float s = (p + i < o1) ? 1.0f : 0.0f;
      acc.x += v[i].x * s; acc.y += v[i].y * s;
      acc.z += v[i].z * s; acc.w += v[i].w * s;
    }
#pragma unroll
    for (int i = 0; i < 4; ++i) { e[i] = n[i]; n[i] = m[i]; v[i] = w[i]; }
  }
  *(float4*)(aggout + (size_t)node * kH + l * 4) =
      make_float4(acc.x * r, acc.y * r, acc.z * r, acc.w * r);
}

// ================= layer-2 gather-mean over layer-1 CSR =================
// node nd (kept id) -> orig row perm[nd]; entries are orig src ids; per-entry
// aux[src] = {keep, score}: scale = keep ? score : 0, mean over kept count.
__global__ __launch_bounds__(256)
void gather2_kernel(const float* __restrict__ feat, const int* __restrict__ ent,
                    const int* __restrict__ off, const int* __restrict__ cursor,
                    const int* __restrict__ perm, const int2* __restrict__ aux,
                    float* __restrict__ aggout, int nloc, int npb) {
  const int xcd   = blockIdx.x & 7;
  const int local = blockIdx.x >> 3;
  const int gsub  = local / npb;
  const int graph = xcd * 8 + gsub;
  const int lane  = threadIdx.x & 63;
  const int h     = lane >> 5;
  const int l     = lane & 31;
  const int wid   = threadIdx.x >> 6;
  const int lnode = (local - gsub * npb) * 8 + wid * 2 + h;
  if (lnode >= nloc) return;
  const int node = graph * nloc + lnode;
  const int orig = perm[node];
  const int o0 = off[orig], o1 = cursor[orig];
  float4 acc = make_float4(0.f, 0.f, 0.f, 0.f);
  int cnt = 0;

  int e[4], n[4];
  int2 a[4];
  float4 v[4];
#pragma unroll
  for (int i = 0; i < 4; ++i) e[i] = eg(ent, o0 + i, o1);
#pragma unroll
  for (int i = 0; i < 4; ++i) {
    v[i] = *(const float4*)(feat + (size_t)e[i] * kH + l * 4);
    a[i] = aux[e[i]];
  }
#pragma unroll
  for (int i = 0; i < 4; ++i) n[i] = eg(ent, o0 + 4 + i, o1);

  for (int p = o0; p < o1; p += 4) {
    int m[4];
    int2 b[4];
    float4 w[4];
#pragma unroll
    for (int i = 0; i < 4; ++i) m[i] = eg(ent, p + 8 + i, o1);
#pragma unroll
    for (int i = 0; i < 4; ++i) {
      w[i] = *(const float4*)(feat + (size_t)n[i] * kH + l * 4);
      b[i] = aux[n[i]];
    }
#pragma unroll
    for (int i = 0; i < 4; ++i) {
      const bool valid = (p + i < o1);
      const int keep = valid ? a[i].x : 0;
      cnt += keep;
      const float s = keep ? __int_as_float(a[i].y) : 0.0f;
      acc.x += v[i].x * s; acc.y += v[i].y * s;
      acc.z += v[i].z * s; acc.w += v[i].w * s;
    }
#pragma unroll
    for (int i = 0; i < 4; ++i) { e[i] = n[i]; n[i] = m[i]; v[i] = w[i]; a[i] = b[i]; }
  }
  const float r = 1.0f / fmaxf((float)cnt, 1.0f);
  *(float4*)(aggout + (size_t)node * kH + l * 4) =
      make_float4(acc.x * r, acc.y * r, acc.z * r, acc.w * r);
}

// ================= split-bf16 MFMA SAGE GEMM + fused score =================
// out = relu([mean | gated-x] @ [Wl;Wr] + b); scr[row] = tanh(out_row . pwn)
// Score partials: each wave covers 64 cols; cross-wave combine via sdot LDS.
__global__ __launch_bounds__(256)
void sage_gemm_mfma(const float* __restrict__ meanb, const float* __restrict__ xsrc,
                    const int* __restrict__ perm, const float* __restrict__ gsc,
                    const ushort* __restrict__ WTh, const ushort* __restrict__ WTl,
                    const float* __restrict__ bias, const float* __restrict__ pwn,
                    float* __restrict__ outp, float* __restrict__ scr) {
  __shared__ __align__(16) ushort aH[128][32];   // [row][k], 64 B row stride
  __shared__ __align__(16) ushort aL[128][32];
  __shared__ __align__(16) ushort wHs[128][32];  // [n][k] (= W^T)
  __shared__ __align__(16) ushort wLs[128][32];
  __shared__ float sdot[128][2];                 // [row][col-half] score partials
  const int tid  = threadIdx.x;
  const int wid  = tid >> 6;
  const int lane = tid & 63;
  const int quad = lane >> 4;
  const int l16  = lane & 15;
  const int rowbase = blockIdx.x * 128;
  const int wr = (wid >> 1) * 64;
  const int wc = (wid & 1) * 64;

  f32x4 acc[4][4];
#pragma unroll
  for (int a = 0; a < 4; ++a)
#pragma unroll
    for (int b = 0; b < 4; ++b) acc[a][b] = (f32x4){0.f, 0.f, 0.f, 0.f};

  for (int s = 0; s < 8; ++s) {                  // 8 k-steps of 32 over K=256
    const bool ismean = s < 4;
    const float* sp = ismean ? meanb : xsrc;
    const int kbase = s * 32;
    const int kloc  = ismean ? kbase : kbase - 128;
#pragma unroll
    for (int i = 0; i < 4; ++i) {
      const int p   = tid + i * 256;
      const int row = p >> 3;
      const int k4  = (p & 7) * 4;
      const int grow = rowbase + row;
      int srow = grow; float scale = 1.0f;
      if (!ismean && perm) { srow = perm[grow]; scale = gsc[grow]; }
      const float4 v = *(const float4*)(sp + (size_t)srow * kH + kloc + k4);
      float f[4] = {v.x * scale, v.y * scale, v.z * scale, v.w * scale};
      ushort4 hv, lv;
      hv.x = f2bf(f[0]); lv.x = f2bf(f[0] - bf2f(hv.x));
      hv.y = f2bf(f[1]); lv.y = f2bf(f[1] - bf2f(hv.y));
      hv.z = f2bf(f[2]); lv.z = f2bf(f[2] - bf2f(hv.z));
      hv.w = f2bf(f[3]); lv.w = f2bf(f[3] - bf2f(hv.w));
      *(ushort4*)&aH[row][k4] = hv;
      *(ushort4*)&aL[row][k4] = lv;
    }
#pragma unroll
    for (int i = 0; i < 4; ++i) {
      const int p  = tid + i * 256;
      const int n  = p >> 3;
      const int k4 = (p & 7) * 4;
      *(ushort4*)&wHs[n][k4] = *(const ushort4*)(WTh + n * 256 + kbase + k4);
      *(ushort4*)&wLs[n][k4] = *(const ushort4*)(WTl + n * 256 + kbase + k4);
    }
    __syncthreads();
    bf16x8 afh[4], afl[4];
#pragma unroll
    for (int rt = 0; rt < 4; ++rt) {
      afh[rt] = *(const bf16x8*)&aH[wr + rt * 16 + l16][quad * 8];
      afl[rt] = *(const bf16x8*)&aL[wr + rt * 16 + l16][quad * 8];
    }
#pragma unroll
    for (int ct = 0; ct < 4; ++ct) {
      const bf16x8 bh = *(const bf16x8*)&wHs[wc + ct * 16 + l16][quad * 8];
      const bf16x8 bl = *(const bf16x8*)&wLs[wc + ct * 16 + l16][quad * 8];
#pragma unroll
      for (int rt = 0; rt < 4; ++rt) {
        acc[rt][ct] = __builtin_amdgcn_mfma_f32_16x16x32_bf16(afh[rt], bh, acc[rt][ct], 0, 0, 0);
        acc[rt][ct] = __builtin_amdgcn_mfma_f32_16x16x32_bf16(afh[rt], bl, acc[rt][ct], 0, 0, 0);
        acc[rt][ct] = __builtin_amdgcn_mfma_f32_16x16x32_bf16(afl[rt], bh, acc[rt][ct], 0, 0, 0);
      }
    }
    __syncthreads();
  }
  // ---- epilogue: bias + relu + store + fused score (64-col partial/wave) ----
  float bv[4], pwv[4];
#pragma unroll
  for (int ct = 0; ct < 4; ++ct) {
    const int col = wc + ct * 16 + l16;
    bv[ct]  = bias[col];
    pwv[ct] = pwn[col];
  }
  float dot[4][4];
#pragma unroll
  for (int rt = 0; rt < 4; ++rt)
#pragma unroll
    for (int reg = 0; reg < 4; ++reg) dot[rt][reg] = 0.0f;
#pragma unroll
  for (int ct = 0; ct < 4; ++ct) {
    const int col = wc + ct * 16 + l16;
#pragma unroll
    for (int rt = 0; rt < 4; ++rt) {
#pragma unroll
      for (int reg = 0; reg < 4; ++reg) {
        const int row = rowbase + wr + rt * 16 + quad * 4 + reg;
        const float o = fmaxf(acc[rt][ct][reg] + bv[ct], 0.0f);
        outp[(size_t)row * kH + col] = o;
        dot[rt][reg] += o * pwv[ct];
      }
    }
  }
  // reduce over the 16 l16-lanes (xor 1,2,4,8 stays inside the quad group)
#pragma unroll
  for (int rt = 0; rt < 4; ++rt) {
#pragma unroll
    for (int reg = 0; reg < 4; ++reg) {
      float d = dot[rt][reg];
      d += __shfl_xor(d, 1);
      d += __shfl_xor(d, 2);
      d += __shfl_xor(d, 4);
      d += __shfl_xor(d, 8);
      if (l16 == 0) sdot[wr + rt * 16 + quad * 4 + reg][wc >> 6] = d;
    }
  }
  __syncthreads();
  if (tid < 128) scr[rowbase + tid] = tanhf(sdot[tid][0] + sdot[tid][1]);
}

// ---- top-K rank phase: 4 chunk-blocks per graph, one thread per node ----
__global__ __launch_bounds__(256)
void rank_kernel(const float* __restrict__ scr, int n_per, int K,
                 int* __restrict__ kflag) {
  __shared__ __align__(16) float s[1024];
  const int g     = blockIdx.x >> 2;
  const int chunk = blockIdx.x & 3;
  const int tid   = threadIdx.x;
  for (int i = tid; i < 1024; i += 256)
    s[i] = (i < n_per) ? scr[g * n_per + i] : -3e30f;   // pad never outranks
  __syncthreads();
  const int i0 = chunk * 256 + tid;
  if (i0 >= n_per) return;
  const float mys = s[i0];
  int rank = 0;
  for (int j = 0; j < 1024; j += 4) {
    const float4 sj = *(const float4*)&s[j];
    rank += (sj.x > mys) || (sj.x == mys && (j + 0) < i0);
    rank += (sj.y > mys) || (sj.y == mys && (j + 1) < i0);
    rank += (sj.z > mys) || (sj.z == mys && (j + 2) < i0);
    rank += (sj.w > mys) || (sj.w == mys && (j + 3) < i0);
  }
  kflag[g * n_per + i0] = (rank < K) ? 1 : 0;
}

// ---- compaction: per-graph scan of keep flags; aux={keep,score} for layer1 ----
__global__ __launch_bounds__(1024)
void compact_kernel(const float* __restrict__ scr, const int* __restrict__ kflag,
                    int n_per, int K, int* __restrict__ perm,
                    float* __restrict__ gsc, int2* __restrict__ aux) {
  __shared__ int ps[1024];
  const int g = blockIdx.x, i = threadIdx.x;
  const int keep = (i < n_per) ? kflag[g * n_per + i] : 0;
  ps[i] = keep;
  __syncthreads();
  for (int off = 1; off < 1024; off <<= 1) {
    int v = ps[i];
    if (i >= off) v += ps[i - off];
    __syncthreads();
    ps[i] = v;
    __syncthreads();
  }
  if (i < n_per) {
    const float sc = scr[g * n_per + i];
    if (keep) {
      const int pos = ps[i] - 1;
      perm[g * K + pos] = g * n_per + i;
      gsc[g * K + pos]  = sc;
    }
    if (aux) aux[g * n_per + i] = make_int2(keep, __float_as_int(sc));
  }
}

// ---- readout stage 1: per-(graph, row-chunk) partial mean/max over gated rows ----
__global__ __launch_bounds__(256)
void readout_part(const float* __restrict__ h, const int* __restrict__ perm,
                  const float* __restrict__ gsc, int K,
                  float* __restrict__ psum, float* __restrict__ pmax) {
  const int g     = blockIdx.x >> 4;
  const int chunk = blockIdx.x & (kRChunks - 1);
  const int j     = threadIdx.x & 127;
  const int part  = threadIdx.x >> 7;            // 2 parts
  const int rows  = (K + kRChunks - 1) / kRChunks;
  const int r0 = chunk * rows;
  const int r1 = min(r0 + rows, K);
  float sum = 0.0f, mx = -1e30f;
  for (int r = r0 + part; r < r1; r += 2) {
    const int   row = perm[g * K + r];
    const float sc  = gsc[g * K + r];
    const float v   = h[(size_t)row * kH + j] * sc;
    sum += v;
    mx = fmaxf(mx, v);
  }
  __shared__ float ss[2][128], sm[2][128];
  ss[part][j] = sum;
  sm[part][j] = mx;
  __syncthreads();
  if (part == 0) {
    sum += ss[1][j];
    mx = fmaxf(mx, sm[1][j]);
    psum[(size_t)blockIdx.x * 128 + j] = sum;
    pmax[(size_t)blockIdx.x * 128 + j] = mx;
  }
}

// ---- fused: combine readout chunks (both layers) + 2-layer MLP head ----
__global__ __launch_bounds__(128)
void final_mlp(const float* __restrict__ ps1, const float* __restrict__ pm1,
               const float* __restrict__ ps2, const float* __restrict__ pm2,
               const float* __restrict__ fW1, const float* __restrict__ fb1,
               const float* __restrict__ fW2, const float* __restrict__ fb2,
               float* __restrict__ out) {
  __shared__ float xx[256];
  __shared__ float z[128];
  const int g = blockIdx.x, tid = threadIdx.x;
  float s1 = 0.f, m1 = -1e30f, s2 = 0.f, m2 = -1e30f;
#pragma unroll
  for (int c = 0; c < kRChunks; ++c) {
    s1 += ps1[(size_t)(g * kRChunks + c) * 128 + tid];
    m1 = fmaxf(m1, pm1[(size_t)(g * kRChunks + c) * 128 + tid]);
    s2 += ps2[(size_t)(g * kRChunks + c) * 128 + tid];
    m2 = fmaxf(m2, pm2[(size_t)(g * kRChunks + c) * 128 + tid]);
  }
  xx[tid]       = s1 / (float)kK1 + s2 / (float)kK2;
  xx[tid + 128] = m1 + m2;
  __syncthreads();
  float a = fb1[tid];
  for (int k = 0; k < 256; ++k) a += xx[k] * fW1[k * 128 + tid];
  z[tid] = fmaxf(a, 0.0f);
  __syncthreads();
  if (tid < 10) {
    float o = fb2[tid];
    for (int k = 0; k < 128; ++k) o += z[k] * fW2[k * 10 + tid];
    out[g * 10 + tid] = o;
  }
}

}  // namespace

extern "C" void kernel_launch(void* const* d_in, const int* in_sizes, int n_in,
                              void* d_out, int out_size, void* d_ws, size_t ws_size,
                              hipStream_t stream) {
  const float* x   = (const float*)d_in[0];
  const int*   ei  = (const int*)d_in[1];
  const float* Wl1 = (const float*)d_in[3];
  const float* bl1 = (const float*)d_in[4];
  const float* Wr1 = (const float*)d_in[5];
  const float* Wl2 = (const float*)d_in[6];
  const float* bl2 = (const float*)d_in[7];
  const float* Wr2 = (const float*)d_in[8];
  const float* pw1 = (const float*)d_in[9];
  const float* pw2 = (const float*)d_in[10];
  const float* fW1 = (const float*)d_in[11];
  const float* fb1 = (const float*)d_in[12];
  const float* fW2 = (const float*)d_in[13];
  const float* fb2 = (const float*)d_in[14];
  const int* src = ei;
  const int* dst = ei + kE;
  (void)in_sizes; (void)n_in; (void)out_size; (void)ws_size;

  char* wsb = (char*)d_ws;
  size_t off_b = 0;
  auto alloc = [&](size_t bytes) {
    void* p = wsb + off_b;
    off_b += (bytes + 255) & ~(size_t)255;
    return p;
  };
  float* bufA = (float*)alloc((size_t)kM1 * kH * 4);  // mean1 -> mean2
  float* bufB = (float*)alloc((size_t)kM1 * kH * 4);  // h1
  float* bufC = (float*)alloc((size_t)kM2 * kH * 4);  // h2
  int*   deg  = (int*)alloc((size_t)kM1 * 4);
  int*   coff = (int*)alloc((size_t)kM1 * 4);
  int*   ccur = (int*)alloc((size_t)kM1 * 4);
  int*   ent  = (int*)alloc((size_t)kE * 4);
  float* scr  = (float*)alloc((size_t)kM1 * 4);
  int*   kflag= (int*)alloc((size_t)kM1 * 4);
  int2*  aux  = (int2*)alloc((size_t)kM1 * 8);
  int*   perm1= (int*)alloc((size_t)kM2 * 4);
  float* gsc1 = (float*)alloc((size_t)kM2 * 4);
  int*   perm2= (int*)alloc((size_t)kM3 * 4);
  float* gsc2 = (float*)alloc((size_t)kM3 * 4);
  float* psum1= (float*)alloc((size_t)kB * kRChunks * 128 * 4);
  float* pmax1= (float*)alloc((size_t)kB * kRChunks * 128 * 4);
  float* psum2= (float*)alloc((size_t)kB * kRChunks * 128 * 4);
  float* pmax2= (float*)alloc((size_t)kB * kRChunks * 128 * 4);
  ushort* wt1h = (ushort*)alloc((size_t)128 * 256 * 2);
  ushort* wt1l = (ushort*)alloc((size_t)128 * 256 * 2);
  ushort* wt2h = (ushort*)alloc((size_t)128 * 256 * 2);
  ushort* wt2l = (ushort*)alloc((size_t)128 * 256 * 2);
  float* pwn1 = (float*)alloc(128 * 4);
  float* pwn2 = (float*)alloc(128 * 4);

  prep_kernel<<<257, 256, 0, stream>>>(Wl1, Wr1, Wl2, Wr2, pw1, pw2,
                                       wt1h, wt1l, wt2h, wt2l, pwn1, pwn2);

  const int npb1 = kN / 8;             // 128
  const int npb2 = (kK1 + 7) / 8;      // 103

  // ---------------- layer 1 ----------------
  hipMemsetAsync(deg, 0, (size_t)kM1 * 4, stream);
  deg_kernel<<<kE / 256, 256, 0, stream>>>(dst, deg);
  scan_kernel<<<kB, 1024, 0, stream>>>(deg, kN, coff, ccur);
  fill1_kernel<<<kE / 256, 256, 0, stream>>>(src, dst, ccur, ent);
  gather1_kernel<<<64 * npb1, 256, 0, stream>>>(x, ent, coff, ccur, bufA, kN, npb1);
  sage_gemm_mfma<<<kM1 / 128, 256, 0, stream>>>(bufA, x, nullptr, nullptr,
                                                wt1h, wt1l, bl1, pwn1, bufB, scr);
  rank_kernel<<<kB * 4, 256, 0, stream>>>(scr, kN, kK1, kflag);
  compact_kernel<<<kB, 1024, 0, stream>>>(scr, kflag, kN, kK1, perm1, gsc1, aux);
  readout_part<<<kB * kRChunks, 256, 0, stream>>>(bufB, perm1, gsc1, kK1, psum1, pmax1);

  // ---------------- layer 2 (reuses layer-1 CSR via aux) ----------------
  gather2_kernel<<<64 * npb2, 256, 0, stream>>>(bufB, ent, coff, ccur, perm1, aux,
                                                bufA, kK1, npb2);
  sage_gemm_mfma<<<kM2 / 128, 256, 0, stream>>>(bufA, bufB, perm1, gsc1,
                                                wt2h, wt2l, bl2, pwn2, bufC, scr);
  rank_kernel<<<kB * 4, 256, 0, stream>>>(scr, kK1, kK2, kflag);
  compact_kernel<<<kB, 1024, 0, stream>>>(scr, kflag, kK1, kK2, perm2, gsc2, nullptr);
  readout_part<<<kB * kRChunks, 256, 0, stream>>>(bufC, perm2, gsc2, kK2, psum2, pmax2);

  // ---------------- head ----------------
  final_mlp<<<kB, 128, 0, stream>>>(psum1, pmax1, psum2, pmax2,
                                    fW1, fb1, fW2, fb2, (float*)d_out);
}